// Round 3
// baseline (805.404 us; speedup 1.0000x reference)
//
#include <hip/hip_runtime.h>
#include <hip/hip_bf16.h>

// Round 3: top-2 routing (4x less expert work), BK=32 double-buffered GEMM
// (no swizzle needed: 64B LDS rows are conflict-free), fast GELU for experts,
// conflict-free LN reduction layout. Gate path numerics unchanged (exact).
#define N_TOK 16384
#define MAX_SLOTS 33792   // 32768 + 8*128 worst-case padding
#define MAX_BLOCKS 264    // sum ceil(cnt_e/128) <= 32768/128 + 8

typedef __attribute__((ext_vector_type(8))) short bf16x8;
typedef __attribute__((ext_vector_type(4))) float f32x4;
typedef unsigned short u16;

__device__ __forceinline__ u16 f2bf(float f) {
  __hip_bfloat16 h = __float2bfloat16(f);
  union { __hip_bfloat16 b; u16 u; } c; c.b = h; return c.u;
}
__device__ __forceinline__ float bfbits2f(u16 u) {
  return __uint_as_float(((unsigned)u) << 16);
}
__device__ __forceinline__ float gelu_erf(float x) {
  return 0.5f * x * (1.0f + erff(x * 0.70710678118654752f));
}
// tanh-approx GELU = x*sigmoid(2u), u = 0.7978846*(x+0.044715x^3); max |err| ~3e-4
__device__ __forceinline__ float gelu_fast(float x) {
  float u = x * (0.79788456f + 0.035677408f * x * x);
  float ex;
  asm("v_exp_f32 %0, %1" : "=v"(ex) : "v"(-2.8853901f * u));  // 2^(-2u*log2e)
  float den = 1.0f + ex;
  float r;
  asm("v_rcp_f32 %0, %1" : "=v"(r) : "v"(den));
  return x * r;
}
__device__ __forceinline__ void gload16(const u16* g, char* lds) {
  __builtin_amdgcn_global_load_lds(
      (const __attribute__((address_space(1))) void*)g,
      (__attribute__((address_space(3))) void*)lds, 16, 0, 0);
}

// ---------------------------------------------------------------------------
// prep kernels (unchanged from round 2)
// ---------------------------------------------------------------------------
__global__ __launch_bounds__(256) void prep_x(const float* __restrict__ x,
                                              u16* __restrict__ xbf,
                                              u16* __restrict__ xlo) {
  size_t i = (size_t)blockIdx.x * 256 + threadIdx.x;
  float4 v = ((const float4*)x)[i];
  float a[4] = {v.x, v.y, v.z, v.w};
  union { u16 us[4]; unsigned long long ll; } hb, lb;
#pragma unroll
  for (int j = 0; j < 4; ++j) {
    u16 hu = f2bf(a[j]);
    hb.us[j] = hu;
    lb.us[j] = f2bf(a[j] - bfbits2f(hu));
  }
  *(unsigned long long*)(xbf + i * 4) = hb.ll;
  *(unsigned long long*)(xlo + i * 4) = lb.ll;
}

__global__ __launch_bounds__(256) void transpose_bf_tiled(
    const float* __restrict__ src, u16* __restrict__ dst, int R, int C) {
  __shared__ float t[64][65];
  const int e = blockIdx.z;
  const int r0 = blockIdx.x * 64, c0 = blockIdx.y * 64;
  const float* s = src + (size_t)e * R * C;
  const int tr = threadIdx.x >> 2;
  const int tc4 = (threadIdx.x & 3) * 16;
#pragma unroll
  for (int j = 0; j < 4; ++j) {
    float4 v = *(const float4*)(s + (size_t)(r0 + tr) * C + c0 + tc4 + j * 4);
    t[tr][tc4 + j * 4 + 0] = v.x;
    t[tr][tc4 + j * 4 + 1] = v.y;
    t[tr][tc4 + j * 4 + 2] = v.z;
    t[tr][tc4 + j * 4 + 3] = v.w;
  }
  __syncthreads();
  const int oc = threadIdx.x >> 2;
  union { u16 us[16]; unsigned long long ll[4]; } o;
#pragma unroll
  for (int j = 0; j < 16; ++j) o.us[j] = f2bf(t[tc4 + j][oc]);
  unsigned long long* d =
      (unsigned long long*)(dst + (size_t)e * R * C + (size_t)(c0 + oc) * R + r0 + tc4);
#pragma unroll
  for (int j = 0; j < 4; ++j) d[j] = o.ll[j];
}

__global__ __launch_bounds__(256) void prep_wcat(const float* __restrict__ gw1,
                                                 u16* __restrict__ wcat) {
  int i = blockIdx.x * 256 + threadIdx.x;
  int n = i / 1536, k = i % 1536;
  u16 o;
  if (k < 512) {
    o = f2bf(gw1[k * 512 + n]);
  } else if (k < 1024) {
    float w = gw1[(k - 512) * 512 + n];
    o = f2bf(w - bfbits2f(f2bf(w)));
  } else {
    o = f2bf(gw1[(k - 1024) * 512 + n]);
  }
  wcat[i] = o;
}

__global__ __launch_bounds__(256) void prep_w2t(const float* __restrict__ gw2,
                                                float* __restrict__ w2t) {
  int i = blockIdx.x * 256 + threadIdx.x;
  int e = i >> 9, k = i & 511;
  w2t[i] = gw2[k * 8 + e];
}

// ---------------------------------------------------------------------------
// core GEMM + LN + GELU.  BM = FM*32, BN = 512 (full row for LN), BK = 32,
// 1024 threads (16 waves, 64-wide n-split).  Double-buffered k-loop:
//   STAGE(t+1) ; ds_read+MFMA(t) ; __syncthreads()
// LDS rows are 64B -> naturally conflict-free for both gload writes and reads.
// ---------------------------------------------------------------------------
template <int FM, int ROUTED, int GATHER, int FAST>
__global__ __launch_bounds__(1024) void gemm_core(
    const u16* __restrict__ A, const u16* __restrict__ A2,
    const u16* __restrict__ Wt, long w_estride,
    const float* __restrict__ bias, int b_estride,
    const float* __restrict__ lng, const float* __restrict__ lnb,
    u16* __restrict__ outb, float* __restrict__ outf, int K,
    const int* __restrict__ slot_token, const int* __restrict__ blk_e,
    const int* __restrict__ blk_tok0) {
  constexpr int BM = FM * 32;
  constexpr int AG = FM * 2;            // A row-groups of 16
  constexpr int ABYTES = AG * 1024;     // A tile bytes (BM*64)
  constexpr int BUF = ABYTES + 32768;   // + B tile (512*64B)
  extern __shared__ char smem[];

  const int tid = threadIdx.x;
  const int lane = tid & 63;
  const int wv = tid >> 6;              // 0..15
  const int wm = (wv & 1) * (FM * 16);  // wave m-origin
  const int wn = (wv >> 1) * 64;        // wave n-origin
  const int l15 = lane & 15;
  const int lk = lane >> 4;

  int e, row0;
  if (ROUTED) {
    e = blk_e[blockIdx.x];
    if (e < 0) return;
    row0 = blk_tok0[blockIdx.x];
  } else {
    e = blockIdx.y;
    row0 = blockIdx.x * BM;
  }
  const u16* We = Wt + (size_t)e * w_estride;

  // ---- staging setup: wave handles ids {wv, wv+16, wv+32} < AG+32 ----
  const int lrq = lane >> 2;      // row within 16-row group
  const int lch = (lane & 3) * 8; // element chunk within 32-k row
  const bool hasA = (wv < AG);
  size_t aoff = 0;
  int ldsA = 0, ldsB0 = 0, ldsB1 = 0, ldsB2 = 0;
  const u16 *bp0 = nullptr, *bp1 = nullptr, *bp2 = nullptr;
  if (hasA) {
    int lr = wv * 16 + lrq;
    long grow = GATHER ? (long)slot_token[row0 + lr] : (long)(row0 + lr);
    aoff = (size_t)grow * 512 + lch;
    ldsA = wv * 1024 + lane * 16;
    int g2 = wv + 32 - AG;  // id wv+32 -> B group
    bp2 = We + (size_t)(g2 * 16 + lrq) * K + lch;
    ldsB2 = ABYTES + g2 * 1024 + lane * 16;
  } else {
    int g0 = wv - AG;
    bp0 = We + (size_t)(g0 * 16 + lrq) * K + lch;
    ldsB0 = ABYTES + g0 * 1024 + lane * 16;
  }
  {
    int g1 = wv + 16 - AG;
    bp1 = We + (size_t)(g1 * 16 + lrq) * K + lch;
    ldsB1 = ABYTES + g1 * 1024 + lane * 16;
  }

  auto STAGE = [&](int t, char* b) {
    const int k0 = t * 32;
    const u16* Aseg = A;
    int kc = k0;
    if (A2) {
      if (k0 >= 1024) { Aseg = A2; kc = k0 - 1024; }
      else if (k0 >= 512) kc = k0 - 512;
    }
    if (hasA) {
      gload16(Aseg + aoff + kc, b + ldsA);
      gload16(bp2 + k0, b + ldsB2);
    } else {
      gload16(bp0 + k0, b + ldsB0);
    }
    gload16(bp1 + k0, b + ldsB1);
  };

  f32x4 acc[FM][4];
#pragma unroll
  for (int i = 0; i < FM; ++i)
#pragma unroll
    for (int j = 0; j < 4; ++j) acc[i][j] = (f32x4){0.f, 0.f, 0.f, 0.f};

  const int nt = K / 32;
  char* buf0 = smem;
  char* buf1 = smem + BUF;

  STAGE(0, buf0);
  __syncthreads();
  for (int t = 0; t < nt; ++t) {
    char* cur = (t & 1) ? buf1 : buf0;
    char* nxt = (t & 1) ? buf0 : buf1;
    if (t + 1 < nt) STAGE(t + 1, nxt);
    char* cB = cur + ABYTES;
    bf16x8 af[FM];
#pragma unroll
    for (int fm = 0; fm < FM; ++fm)
      af[fm] = *(const bf16x8*)(cur + (wm + fm * 16 + l15) * 64 + lk * 16);
#pragma unroll
    for (int fn = 0; fn < 4; ++fn) {
      bf16x8 bv = *(const bf16x8*)(cB + (wn + fn * 16 + l15) * 64 + lk * 16);
#pragma unroll
      for (int fm = 0; fm < FM; ++fm)
        acc[fm][fn] = __builtin_amdgcn_mfma_f32_16x16x32_bf16(
            af[fm], bv, acc[fm][fn], 0, 0, 0);
    }
    __syncthreads();
  }

  // ---- epilogue: +bias, LN over 512 row, GELU, store ----
  const float* be = bias + (size_t)e * b_estride;
  const float* ge = lng + (size_t)e * b_estride;
  const float* bbe = lnb + (size_t)e * b_estride;
  float bias_v[4], g_v[4], b_v[4];
#pragma unroll
  for (int fn = 0; fn < 4; ++fn) {
    int col = wn + fn * 16 + l15;
    bias_v[fn] = be[col]; g_v[fn] = ge[col]; b_v[fn] = bbe[col];
  }
#pragma unroll
  for (int fm = 0; fm < FM; ++fm)
#pragma unroll
    for (int fn = 0; fn < 4; ++fn)
#pragma unroll
      for (int r = 0; r < 4; ++r) acc[fm][fn][r] += bias_v[fn];

  // conflict-free reduction: redS1[g*BM+row], redS2 offset 8*BM floats
  float* redS1 = (float*)smem;  // aliases buf0 A-region (size 2*8*BM*4 = ABYTES)
  float* redS2 = redS1 + 8 * BM;
  const int g = wv >> 1;
#pragma unroll
  for (int fm = 0; fm < FM; ++fm)
#pragma unroll
    for (int r = 0; r < 4; ++r) {
      float a1 = 0.f, a2 = 0.f;
#pragma unroll
      for (int fn = 0; fn < 4; ++fn) {
        float v = acc[fm][fn][r];
        a1 += v; a2 += v * v;
      }
#pragma unroll
      for (int m = 1; m < 16; m <<= 1) {
        a1 += __shfl_xor(a1, m, 64);
        a2 += __shfl_xor(a2, m, 64);
      }
      if (l15 == 0) {
        int row = wm + fm * 16 + lk * 4 + r;
        redS1[g * BM + row] = a1;
        redS2[g * BM + row] = a2;
      }
    }
  __syncthreads();
#pragma unroll
  for (int fm = 0; fm < FM; ++fm)
#pragma unroll
    for (int r = 0; r < 4; ++r) {
      int row = wm + fm * 16 + lk * 4 + r;
      float S1 = 0.f, S2 = 0.f;
#pragma unroll
      for (int q = 0; q < 8; ++q) {
        S1 += redS1[q * BM + row];
        S2 += redS2[q * BM + row];
      }
      float mu = S1 * (1.0f / 512.0f);
      float var = S2 * (1.0f / 512.0f) - mu * mu;
      float rs = rsqrtf(var + 1e-5f);
      size_t rowg = (size_t)(row0 + row);
#pragma unroll
      for (int fn = 0; fn < 4; ++fn) {
        int col = wn + fn * 16 + l15;
        float v = (acc[fm][fn][r] - mu) * rs * g_v[fn] + b_v[fn];
        v = FAST ? gelu_fast(v) : gelu_erf(v);
        if (outf) outf[rowg * 512 + col] = v;
        else      outb[rowg * 512 + col] = f2bf(v);
      }
    }
}

// ---------------------------------------------------------------------------
// gate GEMM2 (fp32) + softmax + top-2 + per-expert counts
// ---------------------------------------------------------------------------
__global__ __launch_bounds__(256) void gate2_topk(
    const float* __restrict__ gh, const float* __restrict__ w2t,
    const float* __restrict__ b2, float* __restrict__ gwout,
    float* __restrict__ idxout, float* __restrict__ tkwout,
    int* __restrict__ counts) {
  const int lane = threadIdx.x & 63;
  const int wv = threadIdx.x >> 6;
  const int t = blockIdx.x * 4 + wv;
  const float4* xr = (const float4*)(gh + (size_t)t * 512);
  float4 x0 = xr[lane * 2], x1 = xr[lane * 2 + 1];
  float logit[8];
#pragma unroll
  for (int e = 0; e < 8; ++e) {
    const float4* wr = (const float4*)(w2t + e * 512);
    float4 w0 = wr[lane * 2], w1 = wr[lane * 2 + 1];
    float p = x0.x * w0.x + x0.y * w0.y + x0.z * w0.z + x0.w * w0.w +
              x1.x * w1.x + x1.y * w1.y + x1.z * w1.z + x1.w * w1.w;
#pragma unroll
    for (int m = 1; m < 64; m <<= 1) p += __shfl_xor(p, m, 64);
    logit[e] = p + b2[e];
  }
  if (lane == 0) {
    float mx = logit[0];
#pragma unroll
    for (int e = 1; e < 8; ++e) mx = fmaxf(mx, logit[e]);
    float w[8], ssum = 0.f;
#pragma unroll
    for (int e = 0; e < 8; ++e) { w[e] = expf(logit[e] - mx); ssum += w[e]; }
    float inv = 1.0f / ssum;
#pragma unroll
    for (int e = 0; e < 8; ++e) w[e] *= inv;
    float w1v = -1.f, w2v = -1.f; int i1 = 0, i2 = 0;
#pragma unroll
    for (int e = 0; e < 8; ++e) {
      float v = w[e];
      if (v > w1v)      { w2v = w1v; i2 = i1; w1v = v; i1 = e; }
      else if (v > w2v) { w2v = v; i2 = e; }
    }
    float s = w1v + w2v;
#pragma unroll
    for (int e = 0; e < 8; ++e) gwout[t * 8 + e] = w[e];
    idxout[t * 2] = (float)i1; idxout[t * 2 + 1] = (float)i2;
    tkwout[t * 2] = w1v / s;   tkwout[t * 2 + 1] = w2v / s;
    atomicAdd(&counts[i1], 1);
    atomicAdd(&counts[i2], 1);
  }
}

__global__ __launch_bounds__(256) void usage_k(const float* __restrict__ gw,
                                               float* __restrict__ usage) {
  __shared__ float r[256];
  int e = blockIdx.x;
  float s = 0.f;
  for (int t = threadIdx.x; t < N_TOK; t += 256) s += gw[t * 8 + e];
  r[threadIdx.x] = s;
  __syncthreads();
  for (int st = 128; st > 0; st >>= 1) {
    if (threadIdx.x < st) r[threadIdx.x] += r[threadIdx.x + st];
    __syncthreads();
  }
  if (threadIdx.x == 0) usage[e] = r[0] * (1.0f / (float)N_TOK);
}

// ---------------------------------------------------------------------------
// routing kernels
// ---------------------------------------------------------------------------
__global__ __launch_bounds__(64) void k_zero(int* __restrict__ counts) {
  if (threadIdx.x < 8) counts[threadIdx.x] = 0;
}

__global__ __launch_bounds__(64) void k_offsets(
    const int* __restrict__ counts, int* __restrict__ offsets,
    int* __restrict__ pos, int* __restrict__ blk_e, int* __restrict__ blk_tok0) {
  if (threadIdx.x == 0) {
    int off = 0, nb = 0;
    for (int e = 0; e < 8; ++e) {
      offsets[e] = off;
      pos[e] = 0;
      int nbe = (counts[e] + 127) >> 7;
      for (int b = 0; b < nbe; ++b) {
        blk_e[nb] = e;
        blk_tok0[nb] = off + b * 128;
        nb++;
      }
      off += nbe * 128;
    }
    offsets[8] = off;
    for (; nb < MAX_BLOCKS; ++nb) blk_e[nb] = -1;
  }
}

__global__ __launch_bounds__(256) void k_padinit(int* __restrict__ slot_token,
                                                 float* __restrict__ slot_w) {
  int i = blockIdx.x * 256 + threadIdx.x;
  if (i < MAX_SLOTS) { slot_token[i] = 0; slot_w[i] = 0.f; }
}

__global__ __launch_bounds__(256) void k_scatter(
    const float* __restrict__ idxout, const float* __restrict__ tkwout,
    const int* __restrict__ offsets, int* __restrict__ pos,
    int* __restrict__ slot_token, float* __restrict__ slot_w,
    int* __restrict__ tok_slot) {
  int t = blockIdx.x * 256 + threadIdx.x;
#pragma unroll
  for (int k = 0; k < 2; ++k) {
    int e = (int)idxout[t * 2 + k];
    int p = atomicAdd(&pos[e], 1);
    int s = offsets[e] + p;
    slot_token[s] = t;
    slot_w[s] = tkwout[t * 2 + k];
    tok_slot[t * 2 + k] = s;
  }
}

// ---------------------------------------------------------------------------
// GEMM3: eo[slot] = slot_w[slot] * (h2[slot] @ w3[e] + b3[e])   (routed)
// 256 thr, 4 waves (32x64 each), BK=32 dbuf, K=512
// ---------------------------------------------------------------------------
__global__ __launch_bounds__(256) void gemm3_eo(
    const u16* __restrict__ h, const u16* __restrict__ w3t,
    const float* __restrict__ b3, const float* __restrict__ slot_w,
    const int* __restrict__ blk_e, const int* __restrict__ blk_tok0,
    float* __restrict__ eo) {
  __shared__ char smem[2][12288];  // A 8KB + B 4KB per buffer
  int e = blk_e[blockIdx.x];
  if (e < 0) return;
  int row0 = blk_tok0[blockIdx.x];

  const int tid = threadIdx.x;
  const int lane = tid & 63;
  const int wv = tid >> 6;   // 0..3
  const int wm = wv * 32;
  const int l15 = lane & 15, lk = lane >> 4;
  const u16* we = w3t + (size_t)e * 64 * 512;

  const int lrq = lane >> 2;
  const int lch = (lane & 3) * 8;
  // wave loads: A groups wv, wv+4; B group wv
  size_t a0 = (size_t)(row0 + wv * 16 + lrq) * 512 + lch;
  size_t a1 = (size_t)(row0 + (wv + 4) * 16 + lrq) * 512 + lch;
  const u16* bpw = we + (size_t)(wv * 16 + lrq) * 512 + lch;
  const int lds0 = wv * 1024 + lane * 16;
  const int lds1 = (wv + 4) * 1024 + lane * 16;
  const int lds2 = 8192 + wv * 1024 + lane * 16;

  auto STAGE = [&](int t, char* b) {
    int k0 = t * 32;
    gload16(h + a0 + k0, b + lds0);
    gload16(h + a1 + k0, b + lds1);
    gload16(bpw + k0, b + lds2);
  };

  f32x4 acc[2][4];
#pragma unroll
  for (int i = 0; i < 2; ++i)
#pragma unroll
    for (int j = 0; j < 4; ++j) acc[i][j] = (f32x4){0.f, 0.f, 0.f, 0.f};

  STAGE(0, smem[0]);
  __syncthreads();
  for (int t = 0; t < 16; ++t) {
    char* cur = smem[t & 1];
    if (t + 1 < 16) STAGE(t + 1, smem[(t + 1) & 1]);
    char* cB = cur + 8192;
    bf16x8 af[2];
#pragma unroll
    for (int fm = 0; fm < 2; ++fm)
      af[fm] = *(const bf16x8*)(cur + (wm + fm * 16 + l15) * 64 + lk * 16);
#pragma unroll
    for (int fn = 0; fn < 4; ++fn) {
      bf16x8 bv = *(const bf16x8*)(cB + (fn * 16 + l15) * 64 + lk * 16);
#pragma unroll
      for (int fm = 0; fm < 2; ++fm)
        acc[fm][fn] = __builtin_amdgcn_mfma_f32_16x16x32_bf16(
            af[fm], bv, acc[fm][fn], 0, 0, 0);
    }
    __syncthreads();
  }

#pragma unroll
  for (int fm = 0; fm < 2; ++fm)
#pragma unroll
    for (int r = 0; r < 4; ++r) {
      int row = wm + fm * 16 + lk * 4 + r;
      float w = slot_w[row0 + row];
#pragma unroll
      for (int fn = 0; fn < 4; ++fn) {
        int col = fn * 16 + l15;
        eo[(size_t)(row0 + row) * 64 + col] = w * (acc[fm][fn][r] + b3[e * 64 + col]);
      }
    }
}

// ---------------------------------------------------------------------------
// combine (2 slots per token, weights pre-applied) + final 64x64 projection
// 64 tokens per block, 256 threads (4 threads/token, 16 outs each)
// ---------------------------------------------------------------------------
__global__ __launch_bounds__(256) void combine_proj(
    const float* __restrict__ eo, const int* __restrict__ tok_slot,
    const float* __restrict__ pw, const float* __restrict__ pb,
    float* __restrict__ outp) {
  __shared__ float cs[64][68];
  __shared__ float pws[64][68];
  const int t0 = blockIdx.x * 64;
  const int tq = threadIdx.x & 3;
  const int tt = threadIdx.x >> 2;
  // stage p_w
#pragma unroll
  for (int j = 0; j < 4; ++j) {
    float4 v = *(const float4*)(pw + tt * 64 + tq * 16 + j * 4);
    *(float4*)&pws[tt][tq * 16 + j * 4] = v;
  }
  // combine two expert rows
  {
    int t = t0 + tt;
    int s1 = tok_slot[t * 2], s2 = tok_slot[t * 2 + 1];
#pragma unroll
    for (int j = 0; j < 4; ++j) {
      float4 a = *(const float4*)(eo + (size_t)s1 * 64 + tq * 16 + j * 4);
      float4 b = *(const float4*)(eo + (size_t)s2 * 64 + tq * 16 + j * 4);
      float4 c = {a.x + b.x, a.y + b.y, a.z + b.z, a.w + b.w};
      *(float4*)&cs[tt][tq * 16 + j * 4] = c;
    }
  }
  __syncthreads();
  float o[16];
#pragma unroll
  for (int i = 0; i < 16; ++i) o[i] = 0.f;
  for (int j = 0; j < 64; ++j) {
    float c = cs[tt][j];
#pragma unroll
    for (int q4 = 0; q4 < 4; ++q4) {
      float4 p = *(const float4*)&pws[j][tq * 16 + q4 * 4];
      o[q4 * 4 + 0] += c * p.x;
      o[q4 * 4 + 1] += c * p.y;
      o[q4 * 4 + 2] += c * p.z;
      o[q4 * 4 + 3] += c * p.w;
    }
  }
#pragma unroll
  for (int i = 0; i < 16; ++i)
    outp[(size_t)(t0 + tt) * 64 + tq * 16 + i] = o[i] + pb[tq * 16 + i];
}

// ---------------------------------------------------------------------------
extern "C" void kernel_launch(void* const* d_in, const int* in_sizes, int n_in,
                              void* d_out, int out_size, void* d_ws, size_t ws_size,
                              hipStream_t stream) {
  const float* x      = (const float*)d_in[0];
  const float* g_w1   = (const float*)d_in[1];
  const float* g_b1   = (const float*)d_in[2];
  const float* g_lng  = (const float*)d_in[3];
  const float* g_lnb  = (const float*)d_in[4];
  const float* g_w2   = (const float*)d_in[5];
  const float* g_b2   = (const float*)d_in[6];
  const float* e_w1   = (const float*)d_in[7];
  const float* e_b1   = (const float*)d_in[8];
  const float* e_ln1g = (const float*)d_in[9];
  const float* e_ln1b = (const float*)d_in[10];
  const float* e_w2   = (const float*)d_in[11];
  const float* e_b2   = (const float*)d_in[12];
  const float* e_ln2g = (const float*)d_in[13];
  const float* e_ln2b = (const float*)d_in[14];
  const float* e_w3   = (const float*)d_in[15];
  const float* e_b3   = (const float*)d_in[16];
  const float* p_w    = (const float*)d_in[17];
  const float* p_b    = (const float*)d_in[18];

  char* ws = (char*)d_ws;
  u16*   x_bf  = (u16*)(ws);                      // 16 MB
  u16*   x_lo  = (u16*)(ws + (16ull << 20));      // 16 MB
  u16*   e_w1t = (u16*)(ws + (32ull << 20));      // 4 MB
  u16*   e_w2t = (u16*)(ws + (36ull << 20));      // 4 MB
  u16*   e_w3t = (u16*)(ws + (40ull << 20));      // 0.5 MB
  u16*   wcat  = (u16*)(ws + (41ull << 20));      // 1.5 MB
  float* w2t   = (float*)(ws + (43ull << 20));    // 16 KB
  float* gh    = (float*)(ws + (44ull << 20));    // 32 MB
  u16*   h     = (u16*)(ws + (76ull << 20));      // 33 MB (MAX_SLOTS x 512 bf16)
  float* eo    = (float*)(ws + (110ull << 20));   // 8.7 MB (MAX_SLOTS x 64 f32)
  int*   slot_token = (int*)(ws + (119ull << 20));        // 132 KB
  float* slot_w     = (float*)(ws + (119ull << 20) + (1ull << 18));
  int*   tok_slot   = (int*)(ws + (119ull << 20) + (2ull << 18));
  int*   counts     = (int*)(ws + (120ull << 20));        // 8
  int*   offsets    = counts + 16;                        // 9
  int*   pos        = counts + 32;                        // 8
  int*   blk_e      = counts + 64;                        // 264
  int*   blk_tok0   = counts + 64 + MAX_BLOCKS;           // 264
  if (ws_size < (121ull << 20)) return;

  float* fout = (float*)d_out;
  float* o_output = fout;                 // 16384*64
  float* o_gatew  = fout + 1048576;       // 16384*8
  float* o_idx    = fout + 1179648;       // 16384*2
  float* o_topw   = fout + 1212416;       // 16384*2
  float* o_usage  = fout + 1245184;       // 8

  (void)hipFuncSetAttribute((const void*)gemm_core<2, 0, 0, 0>,
                            hipFuncAttributeMaxDynamicSharedMemorySize, 73728);
  (void)hipFuncSetAttribute((const void*)gemm_core<4, 1, 1, 1>,
                            hipFuncAttributeMaxDynamicSharedMemorySize, 81920);
  (void)hipFuncSetAttribute((const void*)gemm_core<4, 1, 0, 1>,
                            hipFuncAttributeMaxDynamicSharedMemorySize, 81920);

  // ---- prep ----
  prep_x<<<8192, 256, 0, stream>>>(x, x_bf, x_lo);
  transpose_bf_tiled<<<dim3(8, 8, 8), 256, 0, stream>>>(e_w1, e_w1t, 512, 512);
  transpose_bf_tiled<<<dim3(8, 8, 8), 256, 0, stream>>>(e_w2, e_w2t, 512, 512);
  transpose_bf_tiled<<<dim3(8, 1, 8), 256, 0, stream>>>(e_w3, e_w3t, 512, 64);
  prep_wcat<<<3072, 256, 0, stream>>>(g_w1, wcat);
  prep_w2t<<<16, 256, 0, stream>>>(g_w2, w2t);
  k_zero<<<1, 64, 0, stream>>>(counts);

  // ---- gate (exact path: split-bf16 K=1536, fp32 epilogue, erf) ----
  gemm_core<2, 0, 0, 0><<<dim3(N_TOK / 64, 1), 1024, 73728, stream>>>(
      x_bf, x_lo, wcat, 0, g_b1, 0, g_lng, g_lnb, nullptr, gh, 1536,
      nullptr, nullptr, nullptr);
  gate2_topk<<<N_TOK / 4, 256, 0, stream>>>(gh, w2t, g_b2, o_gatew, o_idx,
                                            o_topw, counts);
  usage_k<<<8, 256, 0, stream>>>(o_gatew, o_usage);

  // ---- routing ----
  k_offsets<<<1, 64, 0, stream>>>(counts, offsets, pos, blk_e, blk_tok0);
  k_padinit<<<(MAX_SLOTS + 255) / 256, 256, 0, stream>>>(slot_token, slot_w);
  k_scatter<<<N_TOK / 256, 256, 0, stream>>>(o_idx, o_topw, offsets, pos,
                                             slot_token, slot_w, tok_slot);

  // ---- experts on routed tokens only ----
  gemm_core<4, 1, 1, 1><<<MAX_BLOCKS, 1024, 81920, stream>>>(
      x_bf, nullptr, e_w1t, 512 * 512, e_b1, 512, e_ln1g, e_ln1b, h, nullptr,
      512, slot_token, blk_e, blk_tok0);
  gemm_core<4, 1, 0, 1><<<MAX_BLOCKS, 1024, 81920, stream>>>(
      h, nullptr, e_w2t, 512 * 512, e_b2, 512, e_ln2g, e_ln2b, h, nullptr,
      512, slot_token, blk_e, blk_tok0);
  gemm3_eo<<<MAX_BLOCKS, 256, 0, stream>>>(h, e_w3t, e_b3, slot_w, blk_e,
                                           blk_tok0, eo);
  combine_proj<<<N_TOK / 64, 256, 0, stream>>>(eo, tok_slot, p_w, p_b, o_output);
}

// Round 4
// 308.525 us; speedup vs baseline: 2.6105x; 2.6105x over previous
//
#include <hip/hip_runtime.h>
#include <hip/hip_bf16.h>

// Round 4: hierarchical routing histogram (no same-address global atomics),
// gate GEMM to BM=128. Expert GEMM structure unchanged from round 3.
#define N_TOK 16384
#define MAX_SLOTS 33792   // 32768 + 8*128 worst-case padding
#define MAX_BLOCKS 264    // sum ceil(cnt_e/128) <= 32768/128 + 8

typedef __attribute__((ext_vector_type(8))) short bf16x8;
typedef __attribute__((ext_vector_type(4))) float f32x4;
typedef unsigned short u16;

__device__ __forceinline__ u16 f2bf(float f) {
  __hip_bfloat16 h = __float2bfloat16(f);
  union { __hip_bfloat16 b; u16 u; } c; c.b = h; return c.u;
}
__device__ __forceinline__ float bfbits2f(u16 u) {
  return __uint_as_float(((unsigned)u) << 16);
}
__device__ __forceinline__ float gelu_erf(float x) {
  return 0.5f * x * (1.0f + erff(x * 0.70710678118654752f));
}
// tanh-approx GELU = x*sigmoid(2u), u = 0.7978846*(x+0.044715x^3); max |err| ~3e-4
__device__ __forceinline__ float gelu_fast(float x) {
  float u = x * (0.79788456f + 0.035677408f * x * x);
  float ex;
  asm("v_exp_f32 %0, %1" : "=v"(ex) : "v"(-2.8853901f * u));  // 2^(-2u*log2e)
  float den = 1.0f + ex;
  float r;
  asm("v_rcp_f32 %0, %1" : "=v"(r) : "v"(den));
  return x * r;
}
__device__ __forceinline__ void gload16(const u16* g, char* lds) {
  __builtin_amdgcn_global_load_lds(
      (const __attribute__((address_space(1))) void*)g,
      (__attribute__((address_space(3))) void*)lds, 16, 0, 0);
}

// ---------------------------------------------------------------------------
// prep kernels
// ---------------------------------------------------------------------------
__global__ __launch_bounds__(256) void prep_x(const float* __restrict__ x,
                                              u16* __restrict__ xbf,
                                              u16* __restrict__ xlo) {
  size_t i = (size_t)blockIdx.x * 256 + threadIdx.x;
  float4 v = ((const float4*)x)[i];
  float a[4] = {v.x, v.y, v.z, v.w};
  union { u16 us[4]; unsigned long long ll; } hb, lb;
#pragma unroll
  for (int j = 0; j < 4; ++j) {
    u16 hu = f2bf(a[j]);
    hb.us[j] = hu;
    lb.us[j] = f2bf(a[j] - bfbits2f(hu));
  }
  *(unsigned long long*)(xbf + i * 4) = hb.ll;
  *(unsigned long long*)(xlo + i * 4) = lb.ll;
}

__global__ __launch_bounds__(256) void transpose_bf_tiled(
    const float* __restrict__ src, u16* __restrict__ dst, int R, int C) {
  __shared__ float t[64][65];
  const int e = blockIdx.z;
  const int r0 = blockIdx.x * 64, c0 = blockIdx.y * 64;
  const float* s = src + (size_t)e * R * C;
  const int tr = threadIdx.x >> 2;
  const int tc4 = (threadIdx.x & 3) * 16;
#pragma unroll
  for (int j = 0; j < 4; ++j) {
    float4 v = *(const float4*)(s + (size_t)(r0 + tr) * C + c0 + tc4 + j * 4);
    t[tr][tc4 + j * 4 + 0] = v.x;
    t[tr][tc4 + j * 4 + 1] = v.y;
    t[tr][tc4 + j * 4 + 2] = v.z;
    t[tr][tc4 + j * 4 + 3] = v.w;
  }
  __syncthreads();
  const int oc = threadIdx.x >> 2;
  union { u16 us[16]; unsigned long long ll[4]; } o;
#pragma unroll
  for (int j = 0; j < 16; ++j) o.us[j] = f2bf(t[tc4 + j][oc]);
  unsigned long long* d =
      (unsigned long long*)(dst + (size_t)e * R * C + (size_t)(c0 + oc) * R + r0 + tc4);
#pragma unroll
  for (int j = 0; j < 4; ++j) d[j] = o.ll[j];
}

__global__ __launch_bounds__(256) void prep_wcat(const float* __restrict__ gw1,
                                                 u16* __restrict__ wcat) {
  int i = blockIdx.x * 256 + threadIdx.x;
  int n = i / 1536, k = i % 1536;
  u16 o;
  if (k < 512) {
    o = f2bf(gw1[k * 512 + n]);
  } else if (k < 1024) {
    float w = gw1[(k - 512) * 512 + n];
    o = f2bf(w - bfbits2f(f2bf(w)));
  } else {
    o = f2bf(gw1[(k - 1024) * 512 + n]);
  }
  wcat[i] = o;
}

__global__ __launch_bounds__(256) void prep_w2t(const float* __restrict__ gw2,
                                                float* __restrict__ w2t) {
  int i = blockIdx.x * 256 + threadIdx.x;
  int e = i >> 9, k = i & 511;
  w2t[i] = gw2[k * 8 + e];
}

// ---------------------------------------------------------------------------
// core GEMM + LN + GELU.  BM = FM*32, BN = 512 (full row for LN), BK = 32,
// 1024 threads (16 waves).  Double-buffered k-loop.
// LDS rows are 64B -> naturally conflict-free for gload writes and reads.
// ---------------------------------------------------------------------------
template <int FM, int ROUTED, int GATHER, int FAST>
__global__ __launch_bounds__(1024) void gemm_core(
    const u16* __restrict__ A, const u16* __restrict__ A2,
    const u16* __restrict__ Wt, long w_estride,
    const float* __restrict__ bias, int b_estride,
    const float* __restrict__ lng, const float* __restrict__ lnb,
    u16* __restrict__ outb, float* __restrict__ outf, int K,
    const int* __restrict__ slot_token, const int* __restrict__ blk_e,
    const int* __restrict__ blk_tok0) {
  constexpr int BM = FM * 32;
  constexpr int AG = FM * 2;            // A row-groups of 16
  constexpr int ABYTES = AG * 1024;     // A tile bytes (BM*64)
  constexpr int BUF = ABYTES + 32768;   // + B tile (512*64B)
  extern __shared__ char smem[];

  const int tid = threadIdx.x;
  const int lane = tid & 63;
  const int wv = tid >> 6;              // 0..15
  const int wm = (wv & 1) * (FM * 16);  // wave m-origin
  const int wn = (wv >> 1) * 64;        // wave n-origin
  const int l15 = lane & 15;
  const int lk = lane >> 4;

  int e, row0;
  if (ROUTED) {
    e = blk_e[blockIdx.x];
    if (e < 0) return;
    row0 = blk_tok0[blockIdx.x];
  } else {
    e = blockIdx.y;
    row0 = blockIdx.x * BM;
  }
  const u16* We = Wt + (size_t)e * w_estride;

  // ---- staging setup: wave handles ids {wv, wv+16, wv+32} < AG+32 ----
  const int lrq = lane >> 2;      // row within 16-row group
  const int lch = (lane & 3) * 8; // element chunk within 32-k row
  const bool hasA = (wv < AG);
  size_t aoff = 0;
  int ldsA = 0, ldsB0 = 0, ldsB1 = 0, ldsB2 = 0;
  const u16 *bp0 = nullptr, *bp1 = nullptr, *bp2 = nullptr;
  if (hasA) {
    int lr = wv * 16 + lrq;
    long grow = GATHER ? (long)slot_token[row0 + lr] : (long)(row0 + lr);
    aoff = (size_t)grow * 512 + lch;
    ldsA = wv * 1024 + lane * 16;
    int g2 = wv + 32 - AG;  // id wv+32 -> B group
    bp2 = We + (size_t)(g2 * 16 + lrq) * K + lch;
    ldsB2 = ABYTES + g2 * 1024 + lane * 16;
  } else {
    int g0 = wv - AG;
    bp0 = We + (size_t)(g0 * 16 + lrq) * K + lch;
    ldsB0 = ABYTES + g0 * 1024 + lane * 16;
  }
  {
    int g1 = wv + 16 - AG;
    bp1 = We + (size_t)(g1 * 16 + lrq) * K + lch;
    ldsB1 = ABYTES + g1 * 1024 + lane * 16;
  }

  auto STAGE = [&](int t, char* b) {
    const int k0 = t * 32;
    const u16* Aseg = A;
    int kc = k0;
    if (A2) {
      if (k0 >= 1024) { Aseg = A2; kc = k0 - 1024; }
      else if (k0 >= 512) kc = k0 - 512;
    }
    if (hasA) {
      gload16(Aseg + aoff + kc, b + ldsA);
      gload16(bp2 + k0, b + ldsB2);
    } else {
      gload16(bp0 + k0, b + ldsB0);
    }
    gload16(bp1 + k0, b + ldsB1);
  };

  f32x4 acc[FM][4];
#pragma unroll
  for (int i = 0; i < FM; ++i)
#pragma unroll
    for (int j = 0; j < 4; ++j) acc[i][j] = (f32x4){0.f, 0.f, 0.f, 0.f};

  const int nt = K / 32;
  char* buf0 = smem;
  char* buf1 = smem + BUF;

  STAGE(0, buf0);
  __syncthreads();
  for (int t = 0; t < nt; ++t) {
    char* cur = (t & 1) ? buf1 : buf0;
    char* nxt = (t & 1) ? buf0 : buf1;
    if (t + 1 < nt) STAGE(t + 1, nxt);
    char* cB = cur + ABYTES;
    bf16x8 af[FM];
#pragma unroll
    for (int fm = 0; fm < FM; ++fm)
      af[fm] = *(const bf16x8*)(cur + (wm + fm * 16 + l15) * 64 + lk * 16);
#pragma unroll
    for (int fn = 0; fn < 4; ++fn) {
      bf16x8 bv = *(const bf16x8*)(cB + (wn + fn * 16 + l15) * 64 + lk * 16);
#pragma unroll
      for (int fm = 0; fm < FM; ++fm)
        acc[fm][fn] = __builtin_amdgcn_mfma_f32_16x16x32_bf16(
            af[fm], bv, acc[fm][fn], 0, 0, 0);
    }
    __syncthreads();
  }

  // ---- epilogue: +bias, LN over 512 row, GELU, store ----
  const float* be = bias + (size_t)e * b_estride;
  const float* ge = lng + (size_t)e * b_estride;
  const float* bbe = lnb + (size_t)e * b_estride;
  float bias_v[4], g_v[4], b_v[4];
#pragma unroll
  for (int fn = 0; fn < 4; ++fn) {
    int col = wn + fn * 16 + l15;
    bias_v[fn] = be[col]; g_v[fn] = ge[col]; b_v[fn] = bbe[col];
  }
#pragma unroll
  for (int fm = 0; fm < FM; ++fm)
#pragma unroll
    for (int fn = 0; fn < 4; ++fn)
#pragma unroll
      for (int r = 0; r < 4; ++r) acc[fm][fn][r] += bias_v[fn];

  // conflict-free reduction: redS1[g*BM+row], redS2 offset 8*BM floats
  float* redS1 = (float*)smem;
  float* redS2 = redS1 + 8 * BM;
  const int g = wv >> 1;
#pragma unroll
  for (int fm = 0; fm < FM; ++fm)
#pragma unroll
    for (int r = 0; r < 4; ++r) {
      float a1 = 0.f, a2 = 0.f;
#pragma unroll
      for (int fn = 0; fn < 4; ++fn) {
        float v = acc[fm][fn][r];
        a1 += v; a2 += v * v;
      }
#pragma unroll
      for (int m = 1; m < 16; m <<= 1) {
        a1 += __shfl_xor(a1, m, 64);
        a2 += __shfl_xor(a2, m, 64);
      }
      if (l15 == 0) {
        int row = wm + fm * 16 + lk * 4 + r;
        redS1[g * BM + row] = a1;
        redS2[g * BM + row] = a2;
      }
    }
  __syncthreads();
#pragma unroll
  for (int fm = 0; fm < FM; ++fm)
#pragma unroll
    for (int r = 0; r < 4; ++r) {
      int row = wm + fm * 16 + lk * 4 + r;
      float S1 = 0.f, S2 = 0.f;
#pragma unroll
      for (int q = 0; q < 8; ++q) {
        S1 += redS1[q * BM + row];
        S2 += redS2[q * BM + row];
      }
      float mu = S1 * (1.0f / 512.0f);
      float var = S2 * (1.0f / 512.0f) - mu * mu;
      float rs = rsqrtf(var + 1e-5f);
      size_t rowg = (size_t)(row0 + row);
#pragma unroll
      for (int fn = 0; fn < 4; ++fn) {
        int col = wn + fn * 16 + l15;
        float v = (acc[fm][fn][r] - mu) * rs * g_v[fn] + b_v[fn];
        v = FAST ? gelu_fast(v) : gelu_erf(v);
        if (outf) outf[rowg * 512 + col] = v;
        else      outb[rowg * 512 + col] = f2bf(v);
      }
    }
}

// ---------------------------------------------------------------------------
// gate GEMM2 (fp32) + softmax + top-2.  One wave per token. No atomics.
// ---------------------------------------------------------------------------
__global__ __launch_bounds__(256) void gate2_topk(
    const float* __restrict__ gh, const float* __restrict__ w2t,
    const float* __restrict__ b2, float* __restrict__ gwout,
    float* __restrict__ idxout, float* __restrict__ tkwout) {
  const int lane = threadIdx.x & 63;
  const int wv = threadIdx.x >> 6;
  const int t = blockIdx.x * 4 + wv;
  const float4* xr = (const float4*)(gh + (size_t)t * 512);
  float4 x0 = xr[lane * 2], x1 = xr[lane * 2 + 1];
  float logit[8];
#pragma unroll
  for (int e = 0; e < 8; ++e) {
    const float4* wr = (const float4*)(w2t + e * 512);
    float4 w0 = wr[lane * 2], w1 = wr[lane * 2 + 1];
    float p = x0.x * w0.x + x0.y * w0.y + x0.z * w0.z + x0.w * w0.w +
              x1.x * w1.x + x1.y * w1.y + x1.z * w1.z + x1.w * w1.w;
#pragma unroll
    for (int m = 1; m < 64; m <<= 1) p += __shfl_xor(p, m, 64);
    logit[e] = p + b2[e];
  }
  if (lane == 0) {
    float mx = logit[0];
#pragma unroll
    for (int e = 1; e < 8; ++e) mx = fmaxf(mx, logit[e]);
    float w[8], ssum = 0.f;
#pragma unroll
    for (int e = 0; e < 8; ++e) { w[e] = expf(logit[e] - mx); ssum += w[e]; }
    float inv = 1.0f / ssum;
#pragma unroll
    for (int e = 0; e < 8; ++e) w[e] *= inv;
    float w1v = -1.f, w2v = -1.f; int i1 = 0, i2 = 0;
#pragma unroll
    for (int e = 0; e < 8; ++e) {
      float v = w[e];
      if (v > w1v)      { w2v = w1v; i2 = i1; w1v = v; i1 = e; }
      else if (v > w2v) { w2v = v; i2 = e; }
    }
    float s = w1v + w2v;
#pragma unroll
    for (int e = 0; e < 8; ++e) gwout[t * 8 + e] = w[e];
    idxout[t * 2] = (float)i1; idxout[t * 2 + 1] = (float)i2;
    tkwout[t * 2] = w1v / s;   tkwout[t * 2 + 1] = w2v / s;
  }
}

__global__ __launch_bounds__(256) void usage_k(const float* __restrict__ gw,
                                               float* __restrict__ usage) {
  __shared__ float r[256];
  int e = blockIdx.x;
  float s = 0.f;
  for (int t = threadIdx.x; t < N_TOK; t += 256) s += gw[t * 8 + e];
  r[threadIdx.x] = s;
  __syncthreads();
  for (int st = 128; st > 0; st >>= 1) {
    if (threadIdx.x < st) r[threadIdx.x] += r[threadIdx.x + st];
    __syncthreads();
  }
  if (threadIdx.x == 0) usage[e] = r[0] * (1.0f / (float)N_TOK);
}

// ---------------------------------------------------------------------------
// routing: per-block LDS histogram -> parallel offsets -> LDS-ranked scatter.
// No same-address global atomics anywhere.
// ---------------------------------------------------------------------------
__global__ __launch_bounds__(256) void count_hist(const float* __restrict__ idxout,
                                                  int* __restrict__ blk_cnt) {
  __shared__ int h[8];
  if (threadIdx.x < 8) h[threadIdx.x] = 0;
  __syncthreads();
  int t = blockIdx.x * 256 + threadIdx.x;
  int e0 = (int)idxout[t * 2], e1 = (int)idxout[t * 2 + 1];
  atomicAdd(&h[e0], 1);
  atomicAdd(&h[e1], 1);
  __syncthreads();
  if (threadIdx.x < 8) blk_cnt[blockIdx.x * 8 + threadIdx.x] = h[threadIdx.x];
}

__global__ __launch_bounds__(512) void k_offsets2(
    const int* __restrict__ blk_cnt, int* __restrict__ sbase,
    int* __restrict__ blk_e, int* __restrict__ blk_tok0) {
  __shared__ int cnt[64][8];
  __shared__ int ecnt[8];
  __shared__ int offs[8];
  const int tid = threadIdx.x;
  cnt[tid >> 3][tid & 7] = blk_cnt[tid];
  __syncthreads();
  if (tid < 8) {
    int s = 0;
    for (int b = 0; b < 64; ++b) s += cnt[b][tid];
    ecnt[tid] = s;
  }
  __syncthreads();
  if (tid == 0) {
    int off = 0;
    for (int e = 0; e < 8; ++e) {
      offs[e] = off;
      off += ((ecnt[e] + 127) >> 7) << 7;
    }
  }
  __syncthreads();
  {
    int b = tid >> 3, e = tid & 7;
    int s = offs[e];
    for (int bp = 0; bp < b; ++bp) s += cnt[bp][e];
    sbase[tid] = s;
  }
  if (tid < MAX_BLOCKS) {
    int acc = 0, be = -1, bt = 0;
#pragma unroll
    for (int e = 0; e < 8; ++e) {
      int nbe = (ecnt[e] + 127) >> 7;
      if (tid >= acc && tid < acc + nbe) { be = e; bt = offs[e] + (tid - acc) * 128; }
      acc += nbe;
    }
    blk_e[tid] = be;
    blk_tok0[tid] = bt;
  }
}

__global__ __launch_bounds__(256) void k_padinit(int* __restrict__ slot_token,
                                                 float* __restrict__ slot_w) {
  int i = blockIdx.x * 256 + threadIdx.x;
  if (i < MAX_SLOTS) { slot_token[i] = 0; slot_w[i] = 0.f; }
}

__global__ __launch_bounds__(256) void k_scatter2(
    const float* __restrict__ idxout, const float* __restrict__ tkwout,
    const int* __restrict__ sbase, int* __restrict__ slot_token,
    float* __restrict__ slot_w, int* __restrict__ tok_slot) {
  __shared__ int lpos[8];
  if (threadIdx.x < 8) lpos[threadIdx.x] = 0;
  __syncthreads();
  int t = blockIdx.x * 256 + threadIdx.x;
#pragma unroll
  for (int k = 0; k < 2; ++k) {
    int e = (int)idxout[t * 2 + k];
    int lr = atomicAdd(&lpos[e], 1);
    int s = sbase[blockIdx.x * 8 + e] + lr;
    slot_token[s] = t;
    slot_w[s] = tkwout[t * 2 + k];
    tok_slot[t * 2 + k] = s;
  }
}

// ---------------------------------------------------------------------------
// GEMM3: eo[slot] = slot_w[slot] * (h2[slot] @ w3[e] + b3[e])   (routed)
// ---------------------------------------------------------------------------
__global__ __launch_bounds__(256) void gemm3_eo(
    const u16* __restrict__ h, const u16* __restrict__ w3t,
    const float* __restrict__ b3, const float* __restrict__ slot_w,
    const int* __restrict__ blk_e, const int* __restrict__ blk_tok0,
    float* __restrict__ eo) {
  __shared__ char smem[2][12288];
  int e = blk_e[blockIdx.x];
  if (e < 0) return;
  int row0 = blk_tok0[blockIdx.x];

  const int tid = threadIdx.x;
  const int lane = tid & 63;
  const int wv = tid >> 6;
  const int wm = wv * 32;
  const int l15 = lane & 15, lk = lane >> 4;
  const u16* we = w3t + (size_t)e * 64 * 512;

  const int lrq = lane >> 2;
  const int lch = (lane & 3) * 8;
  size_t a0 = (size_t)(row0 + wv * 16 + lrq) * 512 + lch;
  size_t a1 = (size_t)(row0 + (wv + 4) * 16 + lrq) * 512 + lch;
  const u16* bpw = we + (size_t)(wv * 16 + lrq) * 512 + lch;
  const int lds0 = wv * 1024 + lane * 16;
  const int lds1 = (wv + 4) * 1024 + lane * 16;
  const int lds2 = 8192 + wv * 1024 + lane * 16;

  auto STAGE = [&](int t, char* b) {
    int k0 = t * 32;
    gload16(h + a0 + k0, b + lds0);
    gload16(h + a1 + k0, b + lds1);
    gload16(bpw + k0, b + lds2);
  };

  f32x4 acc[2][4];
#pragma unroll
  for (int i = 0; i < 2; ++i)
#pragma unroll
    for (int j = 0; j < 4; ++j) acc[i][j] = (f32x4){0.f, 0.f, 0.f, 0.f};

  STAGE(0, smem[0]);
  __syncthreads();
  for (int t = 0; t < 16; ++t) {
    char* cur = smem[t & 1];
    if (t + 1 < 16) STAGE(t + 1, smem[(t + 1) & 1]);
    char* cB = cur + 8192;
    bf16x8 af[2];
#pragma unroll
    for (int fm = 0; fm < 2; ++fm)
      af[fm] = *(const bf16x8*)(cur + (wm + fm * 16 + l15) * 64 + lk * 16);
#pragma unroll
    for (int fn = 0; fn < 4; ++fn) {
      bf16x8 bv = *(const bf16x8*)(cB + (fn * 16 + l15) * 64 + lk * 16);
#pragma unroll
      for (int fm = 0; fm < 2; ++fm)
        acc[fm][fn] = __builtin_amdgcn_mfma_f32_16x16x32_bf16(
            af[fm], bv, acc[fm][fn], 0, 0, 0);
    }
    __syncthreads();
  }

#pragma unroll
  for (int fm = 0; fm < 2; ++fm)
#pragma unroll
    for (int r = 0; r < 4; ++r) {
      int row = wm + fm * 16 + lk * 4 + r;
      float w = slot_w[row0 + row];
#pragma unroll
      for (int fn = 0; fn < 4; ++fn) {
        int col = fn * 16 + l15;
        eo[(size_t)(row0 + row) * 64 + col] = w * (acc[fm][fn][r] + b3[e * 64 + col]);
      }
    }
}

// ---------------------------------------------------------------------------
// combine (2 slots per token, weights pre-applied) + final 64x64 projection
// ---------------------------------------------------------------------------
__global__ __launch_bounds__(256) void combine_proj(
    const float* __restrict__ eo, const int* __restrict__ tok_slot,
    const float* __restrict__ pw, const float* __restrict__ pb,
    float* __restrict__ outp) {
  __shared__ float cs[64][68];
  __shared__ float pws[64][68];
  const int t0 = blockIdx.x * 64;
  const int tq = threadIdx.x & 3;
  const int tt = threadIdx.x >> 2;
#pragma unroll
  for (int j = 0; j < 4; ++j) {
    float4 v = *(const float4*)(pw + tt * 64 + tq * 16 + j * 4);
    *(float4*)&pws[tt][tq * 16 + j * 4] = v;
  }
  {
    int t = t0 + tt;
    int s1 = tok_slot[t * 2], s2 = tok_slot[t * 2 + 1];
#pragma unroll
    for (int j = 0; j < 4; ++j) {
      float4 a = *(const float4*)(eo + (size_t)s1 * 64 + tq * 16 + j * 4);
      float4 b = *(const float4*)(eo + (size_t)s2 * 64 + tq * 16 + j * 4);
      float4 c = {a.x + b.x, a.y + b.y, a.z + b.z, a.w + b.w};
      *(float4*)&cs[tt][tq * 16 + j * 4] = c;
    }
  }
  __syncthreads();
  float o[16];
#pragma unroll
  for (int i = 0; i < 16; ++i) o[i] = 0.f;
  for (int j = 0; j < 64; ++j) {
    float c = cs[tt][j];
#pragma unroll
    for (int q4 = 0; q4 < 4; ++q4) {
      float4 p = *(const float4*)&pws[j][tq * 16 + q4 * 4];
      o[q4 * 4 + 0] += c * p.x;
      o[q4 * 4 + 1] += c * p.y;
      o[q4 * 4 + 2] += c * p.z;
      o[q4 * 4 + 3] += c * p.w;
    }
  }
#pragma unroll
  for (int i = 0; i < 16; ++i)
    outp[(size_t)(t0 + tt) * 64 + tq * 16 + i] = o[i] + pb[tq * 16 + i];
}

// ---------------------------------------------------------------------------
extern "C" void kernel_launch(void* const* d_in, const int* in_sizes, int n_in,
                              void* d_out, int out_size, void* d_ws, size_t ws_size,
                              hipStream_t stream) {
  const float* x      = (const float*)d_in[0];
  const float* g_w1   = (const float*)d_in[1];
  const float* g_b1   = (const float*)d_in[2];
  const float* g_lng  = (const float*)d_in[3];
  const float* g_lnb  = (const float*)d_in[4];
  const float* g_w2   = (const float*)d_in[5];
  const float* g_b2   = (const float*)d_in[6];
  const float* e_w1   = (const float*)d_in[7];
  const float* e_b1   = (const float*)d_in[8];
  const float* e_ln1g = (const float*)d_in[9];
  const float* e_ln1b = (const float*)d_in[10];
  const float* e_w2   = (const float*)d_in[11];
  const float* e_b2   = (const float*)d_in[12];
  const float* e_ln2g = (const float*)d_in[13];
  const float* e_ln2b = (const float*)d_in[14];
  const float* e_w3   = (const float*)d_in[15];
  const float* e_b3   = (const float*)d_in[16];
  const float* p_w    = (const float*)d_in[17];
  const float* p_b    = (const float*)d_in[18];

  char* ws = (char*)d_ws;
  u16*   x_bf  = (u16*)(ws);                      // 16 MB
  u16*   x_lo  = (u16*)(ws + (16ull << 20));      // 16 MB
  u16*   e_w1t = (u16*)(ws + (32ull << 20));      // 4 MB
  u16*   e_w2t = (u16*)(ws + (36ull << 20));      // 4 MB
  u16*   e_w3t = (u16*)(ws + (40ull << 20));      // 0.5 MB
  u16*   wcat  = (u16*)(ws + (41ull << 20));      // 1.5 MB
  float* w2t   = (float*)(ws + (43ull << 20));    // 16 KB
  float* gh    = (float*)(ws + (44ull << 20));    // 32 MB
  u16*   h     = (u16*)(ws + (76ull << 20));      // 33 MB (MAX_SLOTS x 512 bf16)
  float* eo    = (float*)(ws + (110ull << 20));   // 8.7 MB (MAX_SLOTS x 64 f32)
  int*   slot_token = (int*)(ws + (119ull << 20));
  float* slot_w     = (float*)(ws + (119ull << 20) + (1ull << 18));
  int*   tok_slot   = (int*)(ws + (119ull << 20) + (2ull << 18));
  int*   blk_cnt    = (int*)(ws + (120ull << 20));        // 512
  int*   sbase      = blk_cnt + 512;                      // 512
  int*   blk_e      = blk_cnt + 1024;                     // 264
  int*   blk_tok0   = blk_cnt + 1536;                     // 264
  if (ws_size < (121ull << 20)) return;

  float* fout = (float*)d_out;
  float* o_output = fout;                 // 16384*64
  float* o_gatew  = fout + 1048576;       // 16384*8
  float* o_idx    = fout + 1179648;       // 16384*2
  float* o_topw   = fout + 1212416;       // 16384*2
  float* o_usage  = fout + 1245184;       // 8

  (void)hipFuncSetAttribute((const void*)gemm_core<4, 0, 0, 0>,
                            hipFuncAttributeMaxDynamicSharedMemorySize, 81920);
  (void)hipFuncSetAttribute((const void*)gemm_core<4, 1, 1, 1>,
                            hipFuncAttributeMaxDynamicSharedMemorySize, 81920);
  (void)hipFuncSetAttribute((const void*)gemm_core<4, 1, 0, 1>,
                            hipFuncAttributeMaxDynamicSharedMemorySize, 81920);

  // ---- prep ----
  prep_x<<<8192, 256, 0, stream>>>(x, x_bf, x_lo);
  transpose_bf_tiled<<<dim3(8, 8, 8), 256, 0, stream>>>(e_w1, e_w1t, 512, 512);
  transpose_bf_tiled<<<dim3(8, 8, 8), 256, 0, stream>>>(e_w2, e_w2t, 512, 512);
  transpose_bf_tiled<<<dim3(8, 1, 8), 256, 0, stream>>>(e_w3, e_w3t, 512, 64);
  prep_wcat<<<3072, 256, 0, stream>>>(g_w1, wcat);
  prep_w2t<<<16, 256, 0, stream>>>(g_w2, w2t);

  // ---- gate (exact path: split-bf16 K=1536, fp32 epilogue, erf) ----
  gemm_core<4, 0, 0, 0><<<dim3(N_TOK / 128, 1), 1024, 81920, stream>>>(
      x_bf, x_lo, wcat, 0, g_b1, 0, g_lng, g_lnb, nullptr, gh, 1536,
      nullptr, nullptr, nullptr);
  gate2_topk<<<N_TOK / 4, 256, 0, stream>>>(gh, w2t, g_b2, o_gatew, o_idx, o_topw);
  usage_k<<<8, 256, 0, stream>>>(o_gatew, o_usage);

  // ---- routing (hierarchical, no contended global atomics) ----
  count_hist<<<64, 256, 0, stream>>>(o_idx, blk_cnt);
  k_offsets2<<<1, 512, 0, stream>>>(blk_cnt, sbase, blk_e, blk_tok0);
  k_padinit<<<(MAX_SLOTS + 255) / 256, 256, 0, stream>>>(slot_token, slot_w);
  k_scatter2<<<64, 256, 0, stream>>>(o_idx, o_topw, sbase, slot_token, slot_w,
                                     tok_slot);

  // ---- experts on routed tokens only ----
  gemm_core<4, 1, 1, 1><<<MAX_BLOCKS, 1024, 81920, stream>>>(
      x_bf, nullptr, e_w1t, 512 * 512, e_b1, 512, e_ln1g, e_ln1b, h, nullptr,
      512, slot_token, blk_e, blk_tok0);
  gemm_core<4, 1, 0, 1><<<MAX_BLOCKS, 1024, 81920, stream>>>(
      h, nullptr, e_w2t, 512 * 512, e_b2, 512, e_ln2g, e_ln2b, h, nullptr,
      512, slot_token, blk_e, blk_tok0);
  gemm3_eo<<<MAX_BLOCKS, 256, 0, stream>>>(h, e_w3t, e_b3, slot_w, blk_e,
                                           blk_tok0, eo);
  combine_proj<<<N_TOK / 64, 256, 0, stream>>>(eo, tok_slot, p_w, p_b, o_output);
}

// Round 5
// 297.476 us; speedup vs baseline: 2.7075x; 1.0371x over previous
//
#include <hip/hip_runtime.h>
#include <hip/hip_bf16.h>

// Round 5: chunk-XOR LDS swizzle (kills 8-way ds_read conflict of 64B rows),
// wave tile 64x128 (halves LDS read amplification). Experts: BM=128/8 waves;
// gate: BM=64/4 waves (256 blocks = full GPU).
#define N_TOK 16384
#define MAX_SLOTS 33792   // 32768 + 8*128 worst-case padding
#define MAX_BLOCKS 264    // sum ceil(cnt_e/128) <= 32768/128 + 8

typedef __attribute__((ext_vector_type(8))) short bf16x8;
typedef __attribute__((ext_vector_type(4))) float f32x4;
typedef unsigned short u16;

__device__ __forceinline__ u16 f2bf(float f) {
  __hip_bfloat16 h = __float2bfloat16(f);
  union { __hip_bfloat16 b; u16 u; } c; c.b = h; return c.u;
}
__device__ __forceinline__ float bfbits2f(u16 u) {
  return __uint_as_float(((unsigned)u) << 16);
}
__device__ __forceinline__ float gelu_erf(float x) {
  return 0.5f * x * (1.0f + erff(x * 0.70710678118654752f));
}
// tanh-approx GELU = x*sigmoid(2u); max |err| ~3e-4
__device__ __forceinline__ float gelu_fast(float x) {
  float u = x * (0.79788456f + 0.035677408f * x * x);
  float ex;
  asm("v_exp_f32 %0, %1" : "=v"(ex) : "v"(-2.8853901f * u));
  float den = 1.0f + ex;
  float r;
  asm("v_rcp_f32 %0, %1" : "=v"(r) : "v"(den));
  return x * r;
}
__device__ __forceinline__ void gload16(const u16* g, char* lds) {
  __builtin_amdgcn_global_load_lds(
      (const __attribute__((address_space(1))) void*)g,
      (__attribute__((address_space(3))) void*)lds, 16, 0, 0);
}

// ---------------------------------------------------------------------------
// prep kernels
// ---------------------------------------------------------------------------
__global__ __launch_bounds__(256) void prep_x(const float* __restrict__ x,
                                              u16* __restrict__ xbf,
                                              u16* __restrict__ xlo) {
  size_t i = (size_t)blockIdx.x * 256 + threadIdx.x;
  float4 v = ((const float4*)x)[i];
  float a[4] = {v.x, v.y, v.z, v.w};
  union { u16 us[4]; unsigned long long ll; } hb, lb;
#pragma unroll
  for (int j = 0; j < 4; ++j) {
    u16 hu = f2bf(a[j]);
    hb.us[j] = hu;
    lb.us[j] = f2bf(a[j] - bfbits2f(hu));
  }
  *(unsigned long long*)(xbf + i * 4) = hb.ll;
  *(unsigned long long*)(xlo + i * 4) = lb.ll;
}

__global__ __launch_bounds__(256) void transpose_bf_tiled(
    const float* __restrict__ src, u16* __restrict__ dst, int R, int C) {
  __shared__ float t[64][65];
  const int e = blockIdx.z;
  const int r0 = blockIdx.x * 64, c0 = blockIdx.y * 64;
  const float* s = src + (size_t)e * R * C;
  const int tr = threadIdx.x >> 2;
  const int tc4 = (threadIdx.x & 3) * 16;
#pragma unroll
  for (int j = 0; j < 4; ++j) {
    float4 v = *(const float4*)(s + (size_t)(r0 + tr) * C + c0 + tc4 + j * 4);
    t[tr][tc4 + j * 4 + 0] = v.x;
    t[tr][tc4 + j * 4 + 1] = v.y;
    t[tr][tc4 + j * 4 + 2] = v.z;
    t[tr][tc4 + j * 4 + 3] = v.w;
  }
  __syncthreads();
  const int oc = threadIdx.x >> 2;
  union { u16 us[16]; unsigned long long ll[4]; } o;
#pragma unroll
  for (int j = 0; j < 16; ++j) o.us[j] = f2bf(t[tc4 + j][oc]);
  unsigned long long* d =
      (unsigned long long*)(dst + (size_t)e * R * C + (size_t)(c0 + oc) * R + r0 + tc4);
#pragma unroll
  for (int j = 0; j < 4; ++j) d[j] = o.ll[j];
}

__global__ __launch_bounds__(256) void prep_wcat(const float* __restrict__ gw1,
                                                 u16* __restrict__ wcat) {
  int i = blockIdx.x * 256 + threadIdx.x;
  int n = i / 1536, k = i % 1536;
  u16 o;
  if (k < 512) {
    o = f2bf(gw1[k * 512 + n]);
  } else if (k < 1024) {
    float w = gw1[(k - 512) * 512 + n];
    o = f2bf(w - bfbits2f(f2bf(w)));
  } else {
    o = f2bf(gw1[(k - 1024) * 512 + n]);
  }
  wcat[i] = o;
}

__global__ __launch_bounds__(256) void prep_w2t(const float* __restrict__ gw2,
                                                float* __restrict__ w2t) {
  int i = blockIdx.x * 256 + threadIdx.x;
  int e = i >> 9, k = i & 511;
  w2t[i] = gw2[k * 8 + e];
}

// ---------------------------------------------------------------------------
// core GEMM + LN + GELU.  BM = WM*64, BN = 512 (full row for LN), BK = 32.
// WM waves_m x 4 waves_n, each wave computes 64x128 (FM=4, FN=8).
// Chunk-XOR swizzle: LDS slot (row, p) holds global chunk p ^ ((row>>1)&3);
// staging pre-swizzles the GLOBAL source (LDS stays linear for gload_lds),
// reads apply the same XOR -> 2-way max bank aliasing (free).
// ---------------------------------------------------------------------------
template <int WM, int ROUTED, int GATHER, int FAST>
__global__ __launch_bounds__(WM * 256) void gemm_core(
    const u16* __restrict__ A, const u16* __restrict__ A2,
    const u16* __restrict__ Wt, long w_estride,
    const float* __restrict__ bias, int b_estride,
    const float* __restrict__ lng, const float* __restrict__ lnb,
    u16* __restrict__ outb, float* __restrict__ outf, int K,
    const int* __restrict__ slot_token, const int* __restrict__ blk_e,
    const int* __restrict__ blk_tok0) {
  constexpr int BM = WM * 64;
  constexpr int NW = WM * 4;            // waves per block
  constexpr int AGRP = BM / 16;         // A 16-row groups
  constexpr int ABYTES = BM * 64;       // A tile bytes
  constexpr int BUF = ABYTES + 32768;   // + B tile (512 rows x 64B)
  constexpr int NL = AGRP + 32;         // wave-load instructions per k-step
  constexpr int L = NL / NW;            // loads per wave
  extern __shared__ char smem[];

  const int tid = threadIdx.x;
  const int lane = tid & 63;
  const int wv = tid >> 6;
  const int wm = (wv % WM) * 64;
  const int wn = (wv / WM) * 128;
  const int l15 = lane & 15;
  const int lk = lane >> 4;
  const int swzk16 = (lk ^ ((l15 >> 1) & 3)) << 4;  // swizzled chunk byte off

  int e, row0;
  if (ROUTED) {
    e = blk_e[blockIdx.x];
    if (e < 0) return;
    row0 = blk_tok0[blockIdx.x];
  } else {
    e = blockIdx.y;
    row0 = blockIdx.x * BM;
  }
  const u16* We = Wt + (size_t)e * w_estride;

  // ---- staging setup: pre-swizzled global chunk ----
  const int lrq = lane >> 2;                               // row in 16-group
  const int cse = (((lane & 3) ^ ((lane >> 3) & 3)) << 3); // element offset
  size_t off[L];
  int ldsoff[L];
  bool isa[L];
#pragma unroll
  for (int i = 0; i < L; ++i) {
    int id = wv * L + i;
    if (id < AGRP) {
      int lr = id * 16 + lrq;
      long grow = GATHER ? (long)slot_token[row0 + lr] : (long)(row0 + lr);
      off[i] = (size_t)grow * 512 + cse;
      ldsoff[i] = id * 1024 + lane * 16;
      isa[i] = true;
    } else {
      int bg = id - AGRP;
      off[i] = (size_t)(bg * 16 + lrq) * K + cse;
      ldsoff[i] = ABYTES + bg * 1024 + lane * 16;
      isa[i] = false;
    }
  }

  auto STAGE = [&](int t, char* b) {
    const int k0 = t * 32;
    const u16* Aseg = A;
    int kc = k0;
    if (A2) {
      if (k0 >= 1024) { Aseg = A2; kc = k0 - 1024; }
      else if (k0 >= 512) kc = k0 - 512;
    }
#pragma unroll
    for (int i = 0; i < L; ++i) {
      if (isa[i]) gload16(Aseg + off[i] + kc, b + ldsoff[i]);
      else        gload16(We + off[i] + k0, b + ldsoff[i]);
    }
  };

  f32x4 acc[4][8];
#pragma unroll
  for (int i = 0; i < 4; ++i)
#pragma unroll
    for (int j = 0; j < 8; ++j) acc[i][j] = (f32x4){0.f, 0.f, 0.f, 0.f};

  const int nt = K / 32;
  char* buf0 = smem;
  char* buf1 = smem + BUF;

  STAGE(0, buf0);
  __syncthreads();
  for (int t = 0; t < nt; ++t) {
    char* cur = (t & 1) ? buf1 : buf0;
    char* nxt = (t & 1) ? buf0 : buf1;
    if (t + 1 < nt) STAGE(t + 1, nxt);
    char* cB = cur + ABYTES;
    bf16x8 af[4];
#pragma unroll
    for (int fm = 0; fm < 4; ++fm)
      af[fm] = *(const bf16x8*)(cur + (wm + fm * 16 + l15) * 64 + swzk16);
#pragma unroll
    for (int fn = 0; fn < 8; ++fn) {
      bf16x8 bv = *(const bf16x8*)(cB + (wn + fn * 16 + l15) * 64 + swzk16);
#pragma unroll
      for (int fm = 0; fm < 4; ++fm)
        acc[fm][fn] = __builtin_amdgcn_mfma_f32_16x16x32_bf16(
            af[fm], bv, acc[fm][fn], 0, 0, 0);
    }
    __syncthreads();
  }

  // ---- epilogue: +bias, LN over 512 row, GELU, store ----
  const float* be = bias + (size_t)e * b_estride;
  const float* ge = lng + (size_t)e * b_estride;
  const float* bbe = lnb + (size_t)e * b_estride;
  float bias_v[8], g_v[8], b_v[8];
#pragma unroll
  for (int fn = 0; fn < 8; ++fn) {
    int col = wn + fn * 16 + l15;
    bias_v[fn] = be[col]; g_v[fn] = ge[col]; b_v[fn] = bbe[col];
  }
#pragma unroll
  for (int fm = 0; fm < 4; ++fm)
#pragma unroll
    for (int fn = 0; fn < 8; ++fn)
#pragma unroll
      for (int r = 0; r < 4; ++r) acc[fm][fn][r] += bias_v[fn];

  // conflict-free reduction: redS1[g*BM+row] (4 n-groups)
  float* redS1 = (float*)smem;
  float* redS2 = redS1 + 4 * BM;
  const int g = wv / WM;
#pragma unroll
  for (int fm = 0; fm < 4; ++fm)
#pragma unroll
    for (int r = 0; r < 4; ++r) {
      float a1 = 0.f, a2 = 0.f;
#pragma unroll
      for (int fn = 0; fn < 8; ++fn) {
        float v = acc[fm][fn][r];
        a1 += v; a2 += v * v;
      }
#pragma unroll
      for (int m = 1; m < 16; m <<= 1) {
        a1 += __shfl_xor(a1, m, 64);
        a2 += __shfl_xor(a2, m, 64);
      }
      if (l15 == 0) {
        int row = wm + fm * 16 + lk * 4 + r;
        redS1[g * BM + row] = a1;
        redS2[g * BM + row] = a2;
      }
    }
  __syncthreads();
#pragma unroll
  for (int fm = 0; fm < 4; ++fm)
#pragma unroll
    for (int r = 0; r < 4; ++r) {
      int row = wm + fm * 16 + lk * 4 + r;
      float S1 = 0.f, S2 = 0.f;
#pragma unroll
      for (int q = 0; q < 4; ++q) {
        S1 += redS1[q * BM + row];
        S2 += redS2[q * BM + row];
      }
      float mu = S1 * (1.0f / 512.0f);
      float var = S2 * (1.0f / 512.0f) - mu * mu;
      float rs = rsqrtf(var + 1e-5f);
      size_t rowg = (size_t)(row0 + row);
#pragma unroll
      for (int fn = 0; fn < 8; ++fn) {
        int col = wn + fn * 16 + l15;
        float v = (acc[fm][fn][r] - mu) * rs * g_v[fn] + b_v[fn];
        v = FAST ? gelu_fast(v) : gelu_erf(v);
        if (outf) outf[rowg * 512 + col] = v;
        else      outb[rowg * 512 + col] = f2bf(v);
      }
    }
}

// ---------------------------------------------------------------------------
// gate GEMM2 (fp32) + softmax + top-2.  One wave per token. No atomics.
// ---------------------------------------------------------------------------
__global__ __launch_bounds__(256) void gate2_topk(
    const float* __restrict__ gh, const float* __restrict__ w2t,
    const float* __restrict__ b2, float* __restrict__ gwout,
    float* __restrict__ idxout, float* __restrict__ tkwout) {
  const int lane = threadIdx.x & 63;
  const int wv = threadIdx.x >> 6;
  const int t = blockIdx.x * 4 + wv;
  const float4* xr = (const float4*)(gh + (size_t)t * 512);
  float4 x0 = xr[lane * 2], x1 = xr[lane * 2 + 1];
  float logit[8];
#pragma unroll
  for (int e = 0; e < 8; ++e) {
    const float4* wr = (const float4*)(w2t + e * 512);
    float4 w0 = wr[lane * 2], w1 = wr[lane * 2 + 1];
    float p = x0.x * w0.x + x0.y * w0.y + x0.z * w0.z + x0.w * w0.w +
              x1.x * w1.x + x1.y * w1.y + x1.z * w1.z + x1.w * w1.w;
#pragma unroll
    for (int m = 1; m < 64; m <<= 1) p += __shfl_xor(p, m, 64);
    logit[e] = p + b2[e];
  }
  if (lane == 0) {
    float mx = logit[0];
#pragma unroll
    for (int e = 1; e < 8; ++e) mx = fmaxf(mx, logit[e]);
    float w[8], ssum = 0.f;
#pragma unroll
    for (int e = 0; e < 8; ++e) { w[e] = expf(logit[e] - mx); ssum += w[e]; }
    float inv = 1.0f / ssum;
#pragma unroll
    for (int e = 0; e < 8; ++e) w[e] *= inv;
    float w1v = -1.f, w2v = -1.f; int i1 = 0, i2 = 0;
#pragma unroll
    for (int e = 0; e < 8; ++e) {
      float v = w[e];
      if (v > w1v)      { w2v = w1v; i2 = i1; w1v = v; i1 = e; }
      else if (v > w2v) { w2v = v; i2 = e; }
    }
    float s = w1v + w2v;
#pragma unroll
    for (int e = 0; e < 8; ++e) gwout[t * 8 + e] = w[e];
    idxout[t * 2] = (float)i1; idxout[t * 2 + 1] = (float)i2;
    tkwout[t * 2] = w1v / s;   tkwout[t * 2 + 1] = w2v / s;
  }
}

__global__ __launch_bounds__(256) void usage_k(const float* __restrict__ gw,
                                               float* __restrict__ usage) {
  __shared__ float r[256];
  int e = blockIdx.x;
  float s = 0.f;
  for (int t = threadIdx.x; t < N_TOK; t += 256) s += gw[t * 8 + e];
  r[threadIdx.x] = s;
  __syncthreads();
  for (int st = 128; st > 0; st >>= 1) {
    if (threadIdx.x < st) r[threadIdx.x] += r[threadIdx.x + st];
    __syncthreads();
  }
  if (threadIdx.x == 0) usage[e] = r[0] * (1.0f / (float)N_TOK);
}

// ---------------------------------------------------------------------------
// routing: per-block LDS histogram -> parallel offsets -> LDS-ranked scatter.
// ---------------------------------------------------------------------------
__global__ __launch_bounds__(256) void count_hist(const float* __restrict__ idxout,
                                                  int* __restrict__ blk_cnt) {
  __shared__ int h[8];
  if (threadIdx.x < 8) h[threadIdx.x] = 0;
  __syncthreads();
  int t = blockIdx.x * 256 + threadIdx.x;
  int e0 = (int)idxout[t * 2], e1 = (int)idxout[t * 2 + 1];
  atomicAdd(&h[e0], 1);
  atomicAdd(&h[e1], 1);
  __syncthreads();
  if (threadIdx.x < 8) blk_cnt[blockIdx.x * 8 + threadIdx.x] = h[threadIdx.x];
}

__global__ __launch_bounds__(512) void k_offsets2(
    const int* __restrict__ blk_cnt, int* __restrict__ sbase,
    int* __restrict__ blk_e, int* __restrict__ blk_tok0) {
  __shared__ int cnt[64][8];
  __shared__ int ecnt[8];
  __shared__ int offs[8];
  const int tid = threadIdx.x;
  cnt[tid >> 3][tid & 7] = blk_cnt[tid];
  __syncthreads();
  if (tid < 8) {
    int s = 0;
    for (int b = 0; b < 64; ++b) s += cnt[b][tid];
    ecnt[tid] = s;
  }
  __syncthreads();
  if (tid == 0) {
    int off = 0;
    for (int e = 0; e < 8; ++e) {
      offs[e] = off;
      off += ((ecnt[e] + 127) >> 7) << 7;
    }
  }
  __syncthreads();
  {
    int b = tid >> 3, e = tid & 7;
    int s = offs[e];
    for (int bp = 0; bp < b; ++bp) s += cnt[bp][e];
    sbase[tid] = s;
  }
  if (tid < MAX_BLOCKS) {
    int acc = 0, be = -1, bt = 0;
#pragma unroll
    for (int e = 0; e < 8; ++e) {
      int nbe = (ecnt[e] + 127) >> 7;
      if (tid >= acc && tid < acc + nbe) { be = e; bt = offs[e] + (tid - acc) * 128; }
      acc += nbe;
    }
    blk_e[tid] = be;
    blk_tok0[tid] = bt;
  }
}

__global__ __launch_bounds__(256) void k_padinit(int* __restrict__ slot_token,
                                                 float* __restrict__ slot_w) {
  int i = blockIdx.x * 256 + threadIdx.x;
  if (i < MAX_SLOTS) { slot_token[i] = 0; slot_w[i] = 0.f; }
}

__global__ __launch_bounds__(256) void k_scatter2(
    const float* __restrict__ idxout, const float* __restrict__ tkwout,
    const int* __restrict__ sbase, int* __restrict__ slot_token,
    float* __restrict__ slot_w, int* __restrict__ tok_slot) {
  __shared__ int lpos[8];
  if (threadIdx.x < 8) lpos[threadIdx.x] = 0;
  __syncthreads();
  int t = blockIdx.x * 256 + threadIdx.x;
#pragma unroll
  for (int k = 0; k < 2; ++k) {
    int e = (int)idxout[t * 2 + k];
    int lr = atomicAdd(&lpos[e], 1);
    int s = sbase[blockIdx.x * 8 + e] + lr;
    slot_token[s] = t;
    slot_w[s] = tkwout[t * 2 + k];
    tok_slot[t * 2 + k] = s;
  }
}

// ---------------------------------------------------------------------------
// GEMM3: eo[slot] = slot_w[slot] * (h2[slot] @ w3[e] + b3[e])   (routed)
// Same chunk-XOR swizzle as gemm_core.
// ---------------------------------------------------------------------------
__global__ __launch_bounds__(256) void gemm3_eo(
    const u16* __restrict__ h, const u16* __restrict__ w3t,
    const float* __restrict__ b3, const float* __restrict__ slot_w,
    const int* __restrict__ blk_e, const int* __restrict__ blk_tok0,
    float* __restrict__ eo) {
  __shared__ char smem[2][12288];
  int e = blk_e[blockIdx.x];
  if (e < 0) return;
  int row0 = blk_tok0[blockIdx.x];

  const int tid = threadIdx.x;
  const int lane = tid & 63;
  const int wv = tid >> 6;
  const int wm = wv * 32;
  const int l15 = lane & 15, lk = lane >> 4;
  const int swzk16 = (lk ^ ((l15 >> 1) & 3)) << 4;
  const u16* we = w3t + (size_t)e * 64 * 512;

  const int lrq = lane >> 2;
  const int cse = (((lane & 3) ^ ((lane >> 3) & 3)) << 3);
  size_t a0 = (size_t)(row0 + wv * 16 + lrq) * 512 + cse;
  size_t a1 = (size_t)(row0 + (wv + 4) * 16 + lrq) * 512 + cse;
  const u16* bpw = we + (size_t)(wv * 16 + lrq) * 512 + cse;
  const int lds0 = wv * 1024 + lane * 16;
  const int lds1 = (wv + 4) * 1024 + lane * 16;
  const int lds2 = 8192 + wv * 1024 + lane * 16;

  auto STAGE = [&](int t, char* b) {
    int k0 = t * 32;
    gload16(h + a0 + k0, b + lds0);
    gload16(h + a1 + k0, b + lds1);
    gload16(bpw + k0, b + lds2);
  };

  f32x4 acc[2][4];
#pragma unroll
  for (int i = 0; i < 2; ++i)
#pragma unroll
    for (int j = 0; j < 4; ++j) acc[i][j] = (f32x4){0.f, 0.f, 0.f, 0.f};

  STAGE(0, smem[0]);
  __syncthreads();
  for (int t = 0; t < 16; ++t) {
    char* cur = smem[t & 1];
    if (t + 1 < 16) STAGE(t + 1, smem[(t + 1) & 1]);
    char* cB = cur + 8192;
    bf16x8 af[2];
#pragma unroll
    for (int fm = 0; fm < 2; ++fm)
      af[fm] = *(const bf16x8*)(cur + (wm + fm * 16 + l15) * 64 + swzk16);
#pragma unroll
    for (int fn = 0; fn < 4; ++fn) {
      bf16x8 bv = *(const bf16x8*)(cB + (fn * 16 + l15) * 64 + swzk16);
#pragma unroll
      for (int fm = 0; fm < 2; ++fm)
        acc[fm][fn] = __builtin_amdgcn_mfma_f32_16x16x32_bf16(
            af[fm], bv, acc[fm][fn], 0, 0, 0);
    }
    __syncthreads();
  }

#pragma unroll
  for (int fm = 0; fm < 2; ++fm)
#pragma unroll
    for (int r = 0; r < 4; ++r) {
      int row = wm + fm * 16 + lk * 4 + r;
      float w = slot_w[row0 + row];
#pragma unroll
      for (int fn = 0; fn < 4; ++fn) {
        int col = fn * 16 + l15;
        eo[(size_t)(row0 + row) * 64 + col] = w * (acc[fm][fn][r] + b3[e * 64 + col]);
      }
    }
}

// ---------------------------------------------------------------------------
// combine (2 slots per token, weights pre-applied) + final 64x64 projection
// ---------------------------------------------------------------------------
__global__ __launch_bounds__(256) void combine_proj(
    const float* __restrict__ eo, const int* __restrict__ tok_slot,
    const float* __restrict__ pw, const float* __restrict__ pb,
    float* __restrict__ outp) {
  __shared__ float cs[64][68];
  __shared__ float pws[64][68];
  const int t0 = blockIdx.x * 64;
  const int tq = threadIdx.x & 3;
  const int tt = threadIdx.x >> 2;
#pragma unroll
  for (int j = 0; j < 4; ++j) {
    float4 v = *(const float4*)(pw + tt * 64 + tq * 16 + j * 4);
    *(float4*)&pws[tt][tq * 16 + j * 4] = v;
  }
  {
    int t = t0 + tt;
    int s1 = tok_slot[t * 2], s2 = tok_slot[t * 2 + 1];
#pragma unroll
    for (int j = 0; j < 4; ++j) {
      float4 a = *(const float4*)(eo + (size_t)s1 * 64 + tq * 16 + j * 4);
      float4 b = *(const float4*)(eo + (size_t)s2 * 64 + tq * 16 + j * 4);
      float4 c = {a.x + b.x, a.y + b.y, a.z + b.z, a.w + b.w};
      *(float4*)&cs[tt][tq * 16 + j * 4] = c;
    }
  }
  __syncthreads();
  float o[16];
#pragma unroll
  for (int i = 0; i < 16; ++i) o[i] = 0.f;
  for (int j = 0; j < 64; ++j) {
    float c = cs[tt][j];
#pragma unroll
    for (int q4 = 0; q4 < 4; ++q4) {
      float4 p = *(const float4*)&pws[j][tq * 16 + q4 * 4];
      o[q4 * 4 + 0] += c * p.x;
      o[q4 * 4 + 1] += c * p.y;
      o[q4 * 4 + 2] += c * p.z;
      o[q4 * 4 + 3] += c * p.w;
    }
  }
#pragma unroll
  for (int i = 0; i < 16; ++i)
    outp[(size_t)(t0 + tt) * 64 + tq * 16 + i] = o[i] + pb[tq * 16 + i];
}

// ---------------------------------------------------------------------------
extern "C" void kernel_launch(void* const* d_in, const int* in_sizes, int n_in,
                              void* d_out, int out_size, void* d_ws, size_t ws_size,
                              hipStream_t stream) {
  const float* x      = (const float*)d_in[0];
  const float* g_w1   = (const float*)d_in[1];
  const float* g_b1   = (const float*)d_in[2];
  const float* g_lng  = (const float*)d_in[3];
  const float* g_lnb  = (const float*)d_in[4];
  const float* g_w2   = (const float*)d_in[5];
  const float* g_b2   = (const float*)d_in[6];
  const float* e_w1   = (const float*)d_in[7];
  const float* e_b1   = (const float*)d_in[8];
  const float* e_ln1g = (const float*)d_in[9];
  const float* e_ln1b = (const float*)d_in[10];
  const float* e_w2   = (const float*)d_in[11];
  const float* e_b2   = (const float*)d_in[12];
  const float* e_ln2g = (const float*)d_in[13];
  const float* e_ln2b = (const float*)d_in[14];
  const float* e_w3   = (const float*)d_in[15];
  const float* e_b3   = (const float*)d_in[16];
  const float* p_w    = (const float*)d_in[17];
  const float* p_b    = (const float*)d_in[18];

  char* ws = (char*)d_ws;
  u16*   x_bf  = (u16*)(ws);                      // 16 MB
  u16*   x_lo  = (u16*)(ws + (16ull << 20));      // 16 MB
  u16*   e_w1t = (u16*)(ws + (32ull << 20));      // 4 MB
  u16*   e_w2t = (u16*)(ws + (36ull << 20));      // 4 MB
  u16*   e_w3t = (u16*)(ws + (40ull << 20));      // 0.5 MB
  u16*   wcat  = (u16*)(ws + (41ull << 20));      // 1.5 MB
  float* w2t   = (float*)(ws + (43ull << 20));    // 16 KB
  float* gh    = (float*)(ws + (44ull << 20));    // 32 MB
  u16*   h     = (u16*)(ws + (76ull << 20));      // 33 MB
  float* eo    = (float*)(ws + (110ull << 20));   // 8.7 MB
  int*   slot_token = (int*)(ws + (119ull << 20));
  float* slot_w     = (float*)(ws + (119ull << 20) + (1ull << 18));
  int*   tok_slot   = (int*)(ws + (119ull << 20) + (2ull << 18));
  int*   blk_cnt    = (int*)(ws + (120ull << 20));
  int*   sbase      = blk_cnt + 512;
  int*   blk_e      = blk_cnt + 1024;
  int*   blk_tok0   = blk_cnt + 1536;
  if (ws_size < (121ull << 20)) return;

  float* fout = (float*)d_out;
  float* o_output = fout;                 // 16384*64
  float* o_gatew  = fout + 1048576;       // 16384*8
  float* o_idx    = fout + 1179648;       // 16384*2
  float* o_topw   = fout + 1212416;       // 16384*2
  float* o_usage  = fout + 1245184;       // 8

  (void)hipFuncSetAttribute((const void*)gemm_core<1, 0, 0, 0>,
                            hipFuncAttributeMaxDynamicSharedMemorySize, 73728);
  (void)hipFuncSetAttribute((const void*)gemm_core<2, 1, 1, 1>,
                            hipFuncAttributeMaxDynamicSharedMemorySize, 81920);
  (void)hipFuncSetAttribute((const void*)gemm_core<2, 1, 0, 1>,
                            hipFuncAttributeMaxDynamicSharedMemorySize, 81920);

  // ---- prep ----
  prep_x<<<8192, 256, 0, stream>>>(x, x_bf, x_lo);
  transpose_bf_tiled<<<dim3(8, 8, 8), 256, 0, stream>>>(e_w1, e_w1t, 512, 512);
  transpose_bf_tiled<<<dim3(8, 8, 8), 256, 0, stream>>>(e_w2, e_w2t, 512, 512);
  transpose_bf_tiled<<<dim3(8, 1, 8), 256, 0, stream>>>(e_w3, e_w3t, 512, 64);
  prep_wcat<<<3072, 256, 0, stream>>>(g_w1, wcat);
  prep_w2t<<<16, 256, 0, stream>>>(g_w2, w2t);

  // ---- gate (exact path: split-bf16 K=1536, fp32 epilogue, erf) ----
  gemm_core<1, 0, 0, 0><<<dim3(N_TOK / 64, 1), 256, 73728, stream>>>(
      x_bf, x_lo, wcat, 0, g_b1, 0, g_lng, g_lnb, nullptr, gh, 1536,
      nullptr, nullptr, nullptr);
  gate2_topk<<<N_TOK / 4, 256, 0, stream>>>(gh, w2t, g_b2, o_gatew, o_idx, o_topw);
  usage_k<<<8, 256, 0, stream>>>(o_gatew, o_usage);

  // ---- routing (hierarchical, no contended global atomics) ----
  count_hist<<<64, 256, 0, stream>>>(o_idx, blk_cnt);
  k_offsets2<<<1, 512, 0, stream>>>(blk_cnt, sbase, blk_e, blk_tok0);
  k_padinit<<<(MAX_SLOTS + 255) / 256, 256, 0, stream>>>(slot_token, slot_w);
  k_scatter2<<<64, 256, 0, stream>>>(o_idx, o_topw, sbase, slot_token, slot_w,
                                     tok_slot);

  // ---- experts on routed tokens only ----
  gemm_core<2, 1, 1, 1><<<MAX_BLOCKS, 512, 81920, stream>>>(
      x_bf, nullptr, e_w1t, 512 * 512, e_b1, 512, e_ln1g, e_ln1b, h, nullptr,
      512, slot_token, blk_e, blk_tok0);
  gemm_core<2, 1, 0, 1><<<MAX_BLOCKS, 512, 81920, stream>>>(
      h, nullptr, e_w2t, 512 * 512, e_b2, 512, e_ln2g, e_ln2b, h, nullptr,
      512, slot_token, blk_e, blk_tok0);
  gemm3_eo<<<MAX_BLOCKS, 256, 0, stream>>>(h, e_w3t, e_b3, slot_w, blk_e,
                                           blk_tok0, eo);
  combine_proj<<<N_TOK / 64, 256, 0, stream>>>(eo, tok_slot, p_w, p_b, o_output);
}

// Round 7
// 249.692 us; speedup vs baseline: 3.2256x; 1.1914x over previous
//
#include <hip/hip_runtime.h>
#include <hip/hip_bf16.h>

// Round 7: round 6 with the gh1 workspace-offset bug fixed (gh1 must be
// contiguous with gh0: gate split-K half 1 writes at gh0 + N_TOK*512).
#define N_TOK 16384
#define MAX_SLOTS 33280   // 32768 + 8*64 worst-case padding
#define MAX_BLOCKS 520    // sum ceil(cnt_e/64) <= 32768/64 + 8

typedef __attribute__((ext_vector_type(8))) short bf16x8;
typedef __attribute__((ext_vector_type(4))) float f32x4;
typedef unsigned short u16;

__device__ __forceinline__ u16 f2bf(float f) {
  __hip_bfloat16 h = __float2bfloat16(f);
  union { __hip_bfloat16 b; u16 u; } c; c.b = h; return c.u;
}
__device__ __forceinline__ float bfbits2f(u16 u) {
  return __uint_as_float(((unsigned)u) << 16);
}
__device__ __forceinline__ float gelu_erf(float x) {
  return 0.5f * x * (1.0f + erff(x * 0.70710678118654752f));
}
// tanh-approx GELU; max |err| ~3e-4 (experts only; gate keeps erf)
__device__ __forceinline__ float gelu_fast(float x) {
  float u = x * (0.79788456f + 0.035677408f * x * x);
  float ex;
  asm("v_exp_f32 %0, %1" : "=v"(ex) : "v"(-2.8853901f * u));
  float den = 1.0f + ex;
  float r;
  asm("v_rcp_f32 %0, %1" : "=v"(r) : "v"(den));
  return x * r;
}
__device__ __forceinline__ void gload16(const u16* g, char* lds) {
  __builtin_amdgcn_global_load_lds(
      (const __attribute__((address_space(1))) void*)g,
      (__attribute__((address_space(3))) void*)lds, 16, 0, 0);
}

// ---------------------------------------------------------------------------
// prep kernels
// ---------------------------------------------------------------------------
__global__ __launch_bounds__(256) void prep_x(const float* __restrict__ x,
                                              u16* __restrict__ xbf,
                                              u16* __restrict__ xlo) {
  size_t i = (size_t)blockIdx.x * 256 + threadIdx.x;
  float4 v = ((const float4*)x)[i];
  float a[4] = {v.x, v.y, v.z, v.w};
  union { u16 us[4]; unsigned long long ll; } hb, lb;
#pragma unroll
  for (int j = 0; j < 4; ++j) {
    u16 hu = f2bf(a[j]);
    hb.us[j] = hu;
    lb.us[j] = f2bf(a[j] - bfbits2f(hu));
  }
  *(unsigned long long*)(xbf + i * 4) = hb.ll;
  *(unsigned long long*)(xlo + i * 4) = lb.ll;
}

__global__ __launch_bounds__(256) void transpose_bf_tiled(
    const float* __restrict__ src, u16* __restrict__ dst, int R, int C) {
  __shared__ float t[64][65];
  const int e = blockIdx.z;
  const int r0 = blockIdx.x * 64, c0 = blockIdx.y * 64;
  const float* s = src + (size_t)e * R * C;
  const int tr = threadIdx.x >> 2;
  const int tc4 = (threadIdx.x & 3) * 16;
#pragma unroll
  for (int j = 0; j < 4; ++j) {
    float4 v = *(const float4*)(s + (size_t)(r0 + tr) * C + c0 + tc4 + j * 4);
    t[tr][tc4 + j * 4 + 0] = v.x;
    t[tr][tc4 + j * 4 + 1] = v.y;
    t[tr][tc4 + j * 4 + 2] = v.z;
    t[tr][tc4 + j * 4 + 3] = v.w;
  }
  __syncthreads();
  const int oc = threadIdx.x >> 2;
  union { u16 us[16]; unsigned long long ll[4]; } o;
#pragma unroll
  for (int j = 0; j < 16; ++j) o.us[j] = f2bf(t[tc4 + j][oc]);
  unsigned long long* d =
      (unsigned long long*)(dst + (size_t)e * R * C + (size_t)(c0 + oc) * R + r0 + tc4);
#pragma unroll
  for (int j = 0; j < 4; ++j) d[j] = o.ll[j];
}

__global__ __launch_bounds__(256) void prep_wcat(const float* __restrict__ gw1,
                                                 u16* __restrict__ wcat) {
  int i = blockIdx.x * 256 + threadIdx.x;
  int n = i / 1536, k = i % 1536;
  u16 o;
  if (k < 512) {
    o = f2bf(gw1[k * 512 + n]);
  } else if (k < 1024) {
    float w = gw1[(k - 512) * 512 + n];
    o = f2bf(w - bfbits2f(f2bf(w)));
  } else {
    o = f2bf(gw1[(k - 1024) * 512 + n]);
  }
  wcat[i] = o;
}

__global__ __launch_bounds__(256) void prep_w2t(const float* __restrict__ gw2,
                                                float* __restrict__ w2t) {
  int i = blockIdx.x * 256 + threadIdx.x;
  int e = i >> 9, k = i & 511;
  w2t[i] = gw2[k * 8 + e];
}

// ---------------------------------------------------------------------------
// core GEMM.  BM=64, BN=512, BK=32, 512 threads (8 waves, 64x64 wave tile).
// LDS dbuf 72KB -> 2 blocks/CU; launch_bounds(512,4) caps VGPR at 128.
// Chunk-XOR swizzle (0 conflicts).  LNOUT=1: +bias, LN, GELU -> bf16.
// LNOUT=0: raw fp32 partial to outf + blockIdx.y*osplit (gate K-split).
// ---------------------------------------------------------------------------
template <int ROUTED, int GATHER, int LNOUT, int FAST>
__global__ __launch_bounds__(512, 4) void gemm_core(
    const u16* __restrict__ A, const u16* __restrict__ A2,
    const u16* __restrict__ Wt, long w_estride, int kstride, int klen,
    long osplit, const float* __restrict__ bias, int b_estride,
    const float* __restrict__ lng, const float* __restrict__ lnb,
    u16* __restrict__ outb, float* __restrict__ outf,
    const int* __restrict__ slot_token, const int* __restrict__ blk_e,
    const int* __restrict__ blk_tok0) {
  constexpr int ABYTES = 4096;          // 64 rows x 64B
  constexpr int BUF = ABYTES + 32768;   // + 512 rows x 64B
  extern __shared__ char smem[];

  const int tid = threadIdx.x;
  const int lane = tid & 63;
  const int wv = tid >> 6;          // 0..7
  const int wn = wv * 64;
  const int l15 = lane & 15;
  const int lk = lane >> 4;
  const int swzk16 = (lk ^ ((l15 >> 1) & 3)) << 4;

  int e, row0, kbase;
  if (ROUTED) {
    e = blk_e[blockIdx.x];
    if (e < 0) return;
    row0 = blk_tok0[blockIdx.x];
    kbase = 0;
  } else {
    e = 0;
    row0 = blockIdx.x * 64;
    kbase = blockIdx.y * klen;
  }
  const u16* We = Wt + (size_t)e * w_estride;

  // staging: 36 wave-loads (A:4, B:32); wave wv takes ids {wv+8i | i<5, id<36}
  const int lrq = lane >> 2;                               // row in 16-group
  const int cse = (((lane & 3) ^ ((lane >> 3) & 3)) << 3); // pre-swz elem off
  size_t off[5];
  int ldsoff[5], typ[5];  // 0=A 1=B 2=none
#pragma unroll
  for (int i = 0; i < 5; ++i) {
    int id = wv + 8 * i;
    if (id >= 36) { typ[i] = 2; off[i] = 0; ldsoff[i] = 0; continue; }
    if (id < 4) {
      int lr = id * 16 + lrq;
      long grow = GATHER ? (long)slot_token[row0 + lr] : (long)(row0 + lr);
      off[i] = (size_t)grow * 512 + cse;
      ldsoff[i] = id * 1024 + lane * 16;
      typ[i] = 0;
    } else {
      int bg = id - 4;
      off[i] = (size_t)(bg * 16 + lrq) * kstride + cse;
      ldsoff[i] = ABYTES + bg * 1024 + lane * 16;
      typ[i] = 1;
    }
  }

  auto STAGE = [&](int t, char* b) {
    const int kg = kbase + t * 32;
    const u16* Aseg = A;
    int kc = kg;
    if (A2) {
      if (kg >= 1024) { Aseg = A2; kc = kg - 1024; }
      else if (kg >= 512) kc = kg - 512;
    }
#pragma unroll
    for (int i = 0; i < 5; ++i) {
      if (typ[i] == 0)      gload16(Aseg + off[i] + kc, b + ldsoff[i]);
      else if (typ[i] == 1) gload16(We + off[i] + kg, b + ldsoff[i]);
    }
  };

  f32x4 acc[4][4];
#pragma unroll
  for (int i = 0; i < 4; ++i)
#pragma unroll
    for (int j = 0; j < 4; ++j) acc[i][j] = (f32x4){0.f, 0.f, 0.f, 0.f};

  const int nt = klen / 32;
  char* buf0 = smem;
  char* buf1 = smem + BUF;

  STAGE(0, buf0);
  __syncthreads();
  for (int t = 0; t < nt; ++t) {
    char* cur = (t & 1) ? buf1 : buf0;
    char* nxt = (t & 1) ? buf0 : buf1;
    if (t + 1 < nt) STAGE(t + 1, nxt);
    char* cB = cur + ABYTES;
    bf16x8 af[4];
#pragma unroll
    for (int fm = 0; fm < 4; ++fm)
      af[fm] = *(const bf16x8*)(cur + (fm * 16 + l15) * 64 + swzk16);
#pragma unroll
    for (int fn = 0; fn < 4; ++fn) {
      bf16x8 bv = *(const bf16x8*)(cB + (wn + fn * 16 + l15) * 64 + swzk16);
#pragma unroll
      for (int fm = 0; fm < 4; ++fm)
        acc[fm][fn] = __builtin_amdgcn_mfma_f32_16x16x32_bf16(
            af[fm], bv, acc[fm][fn], 0, 0, 0);
    }
    __syncthreads();
  }

  if constexpr (LNOUT) {
    const float* be = bias + (size_t)e * b_estride;
    const float* ge = lng + (size_t)e * b_estride;
    const float* bbe = lnb + (size_t)e * b_estride;
    float bias_v[4], g_v[4], b_v[4];
#pragma unroll
    for (int fn = 0; fn < 4; ++fn) {
      int col = wn + fn * 16 + l15;
      bias_v[fn] = be[col]; g_v[fn] = ge[col]; b_v[fn] = bbe[col];
    }
#pragma unroll
    for (int fm = 0; fm < 4; ++fm)
#pragma unroll
      for (int fn = 0; fn < 4; ++fn)
#pragma unroll
        for (int r = 0; r < 4; ++r) acc[fm][fn][r] += bias_v[fn];

    // cross-wave LN reduction: redS1[wv*64+row] (8 partials per row)
    float* redS1 = (float*)smem;
    float* redS2 = redS1 + 8 * 64;
#pragma unroll
    for (int fm = 0; fm < 4; ++fm)
#pragma unroll
      for (int r = 0; r < 4; ++r) {
        float a1 = 0.f, a2 = 0.f;
#pragma unroll
        for (int fn = 0; fn < 4; ++fn) {
          float v = acc[fm][fn][r];
          a1 += v; a2 += v * v;
        }
#pragma unroll
        for (int m = 1; m < 16; m <<= 1) {
          a1 += __shfl_xor(a1, m, 64);
          a2 += __shfl_xor(a2, m, 64);
        }
        if (l15 == 0) {
          int row = fm * 16 + lk * 4 + r;
          redS1[wv * 64 + row] = a1;
          redS2[wv * 64 + row] = a2;
        }
      }
    __syncthreads();
#pragma unroll
    for (int fm = 0; fm < 4; ++fm)
#pragma unroll
      for (int r = 0; r < 4; ++r) {
        int row = fm * 16 + lk * 4 + r;
        float S1 = 0.f, S2 = 0.f;
#pragma unroll
        for (int q = 0; q < 8; ++q) {
          S1 += redS1[q * 64 + row];
          S2 += redS2[q * 64 + row];
        }
        float mu = S1 * (1.0f / 512.0f);
        float var = S2 * (1.0f / 512.0f) - mu * mu;
        float rs = rsqrtf(var + 1e-5f);
        size_t rowg = (size_t)(row0 + row);
#pragma unroll
        for (int fn = 0; fn < 4; ++fn) {
          int col = wn + fn * 16 + l15;
          float v = (acc[fm][fn][r] - mu) * rs * g_v[fn] + b_v[fn];
          v = FAST ? gelu_fast(v) : gelu_erf(v);
          outb[rowg * 512 + col] = f2bf(v);
        }
      }
  } else {
    float* dst = outf + (size_t)blockIdx.y * osplit;
#pragma unroll
    for (int fm = 0; fm < 4; ++fm)
#pragma unroll
      for (int r = 0; r < 4; ++r) {
        size_t rowg = (size_t)(row0 + fm * 16 + lk * 4 + r);
#pragma unroll
        for (int fn = 0; fn < 4; ++fn)
          dst[rowg * 512 + wn + fn * 16 + l15] = acc[fm][fn][r];
      }
  }
}

// ---------------------------------------------------------------------------
// gate tail: sum K-halves + bias + LN + GELU(erf) + logits + softmax + top-2
// ---------------------------------------------------------------------------
__global__ __launch_bounds__(256) void gate2_topk(
    const float* __restrict__ gh0, const float* __restrict__ gh1,
    const float* __restrict__ b1, const float* __restrict__ lng,
    const float* __restrict__ lnb, const float* __restrict__ w2t,
    const float* __restrict__ b2, float* __restrict__ gwout,
    float* __restrict__ idxout, float* __restrict__ tkwout) {
  const int lane = threadIdx.x & 63;
  const int wv = threadIdx.x >> 6;
  const int t = blockIdx.x * 4 + wv;
  const int c0 = lane * 8;
  float v[8];
  {
    float4 a0 = *(const float4*)(gh0 + (size_t)t * 512 + c0);
    float4 a1 = *(const float4*)(gh0 + (size_t)t * 512 + c0 + 4);
    float4 h0 = *(const float4*)(gh1 + (size_t)t * 512 + c0);
    float4 h1 = *(const float4*)(gh1 + (size_t)t * 512 + c0 + 4);
    float4 bb0 = *(const float4*)(b1 + c0);
    float4 bb1 = *(const float4*)(b1 + c0 + 4);
    v[0] = a0.x + h0.x + bb0.x; v[1] = a0.y + h0.y + bb0.y;
    v[2] = a0.z + h0.z + bb0.z; v[3] = a0.w + h0.w + bb0.w;
    v[4] = a1.x + h1.x + bb1.x; v[5] = a1.y + h1.y + bb1.y;
    v[6] = a1.z + h1.z + bb1.z; v[7] = a1.w + h1.w + bb1.w;
  }
  float s1 = 0.f, s2 = 0.f;
#pragma unroll
  for (int j = 0; j < 8; ++j) { s1 += v[j]; s2 += v[j] * v[j]; }
#pragma unroll
  for (int m = 1; m < 64; m <<= 1) {
    s1 += __shfl_xor(s1, m, 64);
    s2 += __shfl_xor(s2, m, 64);
  }
  float mu = s1 * (1.0f / 512.0f);
  float var = s2 * (1.0f / 512.0f) - mu * mu;
  float rs = rsqrtf(var + 1e-5f);
  float y[8];
  {
    float4 g0 = *(const float4*)(lng + c0);
    float4 g1 = *(const float4*)(lng + c0 + 4);
    float4 q0 = *(const float4*)(lnb + c0);
    float4 q1 = *(const float4*)(lnb + c0 + 4);
    float gg[8] = {g0.x, g0.y, g0.z, g0.w, g1.x, g1.y, g1.z, g1.w};
    float qq[8] = {q0.x, q0.y, q0.z, q0.w, q1.x, q1.y, q1.z, q1.w};
#pragma unroll
    for (int j = 0; j < 8; ++j)
      y[j] = gelu_erf((v[j] - mu) * rs * gg[j] + qq[j]);
  }
  float logit[8];
#pragma unroll
  for (int e = 0; e < 8; ++e) {
    const float4* wr = (const float4*)(w2t + e * 512 + c0);
    float4 w0 = wr[0], w1 = wr[1];
    float p = y[0] * w0.x + y[1] * w0.y + y[2] * w0.z + y[3] * w0.w +
              y[4] * w1.x + y[5] * w1.y + y[6] * w1.z + y[7] * w1.w;
#pragma unroll
    for (int m = 1; m < 64; m <<= 1) p += __shfl_xor(p, m, 64);
    logit[e] = p + b2[e];
  }
  if (lane == 0) {
    float mx = logit[0];
#pragma unroll
    for (int e = 1; e < 8; ++e) mx = fmaxf(mx, logit[e]);
    float w[8], ssum = 0.f;
#pragma unroll
    for (int e = 0; e < 8; ++e) { w[e] = expf(logit[e] - mx); ssum += w[e]; }
    float inv = 1.0f / ssum;
#pragma unroll
    for (int e = 0; e < 8; ++e) w[e] *= inv;
    float w1v = -1.f, w2v = -1.f; int i1 = 0, i2 = 0;
#pragma unroll
    for (int e = 0; e < 8; ++e) {
      float vv = w[e];
      if (vv > w1v)      { w2v = w1v; i2 = i1; w1v = vv; i1 = e; }
      else if (vv > w2v) { w2v = vv; i2 = e; }
    }
    float s = w1v + w2v;
#pragma unroll
    for (int e = 0; e < 8; ++e) gwout[t * 8 + e] = w[e];
    idxout[t * 2] = (float)i1; idxout[t * 2 + 1] = (float)i2;
    tkwout[t * 2] = w1v / s;   tkwout[t * 2 + 1] = w2v / s;
  }
}

__global__ __launch_bounds__(256) void usage_k(const float* __restrict__ gw,
                                               float* __restrict__ usage) {
  __shared__ float r[256];
  int e = blockIdx.x;
  float s = 0.f;
  for (int t = threadIdx.x; t < N_TOK; t += 256) s += gw[t * 8 + e];
  r[threadIdx.x] = s;
  __syncthreads();
  for (int st = 128; st > 0; st >>= 1) {
    if (threadIdx.x < st) r[threadIdx.x] += r[threadIdx.x + st];
    __syncthreads();
  }
  if (threadIdx.x == 0) usage[e] = r[0] * (1.0f / (float)N_TOK);
}

// ---------------------------------------------------------------------------
// routing (hierarchical; 64-row block granularity)
// ---------------------------------------------------------------------------
__global__ __launch_bounds__(256) void count_hist(const float* __restrict__ idxout,
                                                  int* __restrict__ blk_cnt) {
  __shared__ int h[8];
  if (threadIdx.x < 8) h[threadIdx.x] = 0;
  __syncthreads();
  int t = blockIdx.x * 256 + threadIdx.x;
  int e0 = (int)idxout[t * 2], e1 = (int)idxout[t * 2 + 1];
  atomicAdd(&h[e0], 1);
  atomicAdd(&h[e1], 1);
  __syncthreads();
  if (threadIdx.x < 8) blk_cnt[blockIdx.x * 8 + threadIdx.x] = h[threadIdx.x];
}

__global__ __launch_bounds__(512) void k_offsets2(
    const int* __restrict__ blk_cnt, int* __restrict__ sbase,
    int* __restrict__ blk_e, int* __restrict__ blk_tok0) {
  __shared__ int cnt[64][8];
  __shared__ int ecnt[8];
  __shared__ int offs[8];
  const int tid = threadIdx.x;
  cnt[tid >> 3][tid & 7] = blk_cnt[tid];
  __syncthreads();
  if (tid < 8) {
    int s = 0;
    for (int b = 0; b < 64; ++b) s += cnt[b][tid];
    ecnt[tid] = s;
  }
  __syncthreads();
  if (tid == 0) {
    int off = 0;
    for (int e = 0; e < 8; ++e) {
      offs[e] = off;
      off += ((ecnt[e] + 63) >> 6) << 6;
    }
  }
  __syncthreads();
  {
    int b = tid >> 3, e = tid & 7;
    int s = offs[e];
    for (int bp = 0; bp < b; ++bp) s += cnt[bp][e];
    sbase[tid] = s;
  }
  for (int b = tid; b < MAX_BLOCKS; b += 512) {
    int acc = 0, be = -1, bt = 0;
#pragma unroll
    for (int e = 0; e < 8; ++e) {
      int nbe = (ecnt[e] + 63) >> 6;
      if (b >= acc && b < acc + nbe) { be = e; bt = offs[e] + (b - acc) * 64; }
      acc += nbe;
    }
    blk_e[b] = be;
    blk_tok0[b] = bt;
  }
}

__global__ __launch_bounds__(256) void k_padinit(int* __restrict__ slot_token,
                                                 float* __restrict__ slot_w) {
  int i = blockIdx.x * 256 + threadIdx.x;
  if (i < MAX_SLOTS) { slot_token[i] = 0; slot_w[i] = 0.f; }
}

__global__ __launch_bounds__(256) void k_scatter2(
    const float* __restrict__ idxout, const float* __restrict__ tkwout,
    const int* __restrict__ sbase, int* __restrict__ slot_token,
    float* __restrict__ slot_w, int* __restrict__ tok_slot) {
  __shared__ int lpos[8];
  if (threadIdx.x < 8) lpos[threadIdx.x] = 0;
  __syncthreads();
  int t = blockIdx.x * 256 + threadIdx.x;
#pragma unroll
  for (int k = 0; k < 2; ++k) {
    int e = (int)idxout[t * 2 + k];
    int lr = atomicAdd(&lpos[e], 1);
    int s = sbase[blockIdx.x * 8 + e] + lr;
    slot_token[s] = t;
    slot_w[s] = tkwout[t * 2 + k];
    tok_slot[t * 2 + k] = s;
  }
}

// ---------------------------------------------------------------------------
// GEMM3: eo[slot] = slot_w * (h2[slot] @ w3[e] + b3[e]); 64-row blocks.
// ---------------------------------------------------------------------------
__global__ __launch_bounds__(256) void gemm3_eo(
    const u16* __restrict__ h, const u16* __restrict__ w3t,
    const float* __restrict__ b3, const float* __restrict__ slot_w,
    const int* __restrict__ blk_e, const int* __restrict__ blk_tok0,
    float* __restrict__ eo) {
  __shared__ char smem[2][8192];  // A 4KB + B 4KB per buffer
  int e = blk_e[blockIdx.x];
  if (e < 0) return;
  int row0 = blk_tok0[blockIdx.x];

  const int tid = threadIdx.x;
  const int lane = tid & 63;
  const int wv = tid >> 6;   // 0..3
  const int l15 = lane & 15, lk = lane >> 4;
  const int swzk16 = (lk ^ ((l15 >> 1) & 3)) << 4;
  const u16* we = w3t + (size_t)e * 64 * 512;

  const int lrq = lane >> 2;
  const int cse = (((lane & 3) ^ ((lane >> 3) & 3)) << 3);
  size_t aoff = (size_t)(row0 + wv * 16 + lrq) * 512 + cse;
  size_t boff = (size_t)(wv * 16 + lrq) * 512 + cse;
  const int ldsA = wv * 1024 + lane * 16;
  const int ldsB = 4096 + wv * 1024 + lane * 16;

  auto STAGE = [&](int t, char* b) {
    int k0 = t * 32;
    gload16(h + aoff + k0, b + ldsA);
    gload16(we + boff + k0, b + ldsB);
  };

  f32x4 acc[4];
#pragma unroll
  for (int j = 0; j < 4; ++j) acc[j] = (f32x4){0.f, 0.f, 0.f, 0.f};

  STAGE(0, smem[0]);
  __syncthreads();
  for (int t = 0; t < 16; ++t) {
    char* cur = smem[t & 1];
    if (t + 1 < 16) STAGE(t + 1, smem[(t + 1) & 1]);
    char* cB = cur + 4096;
    bf16x8 a = *(const bf16x8*)(cur + (wv * 16 + l15) * 64 + swzk16);
#pragma unroll
    for (int fn = 0; fn < 4; ++fn) {
      bf16x8 bv = *(const bf16x8*)(cB + (fn * 16 + l15) * 64 + swzk16);
      acc[fn] = __builtin_amdgcn_mfma_f32_16x16x32_bf16(a, bv, acc[fn], 0, 0, 0);
    }
    __syncthreads();
  }

#pragma unroll
  for (int r = 0; r < 4; ++r) {
    int row = wv * 16 + lk * 4 + r;
    float w = slot_w[row0 + row];
#pragma unroll
    for (int fn = 0; fn < 4; ++fn) {
      int col = fn * 16 + l15;
      eo[(size_t)(row0 + row) * 64 + col] = w * (acc[fn][r] + b3[e * 64 + col]);
    }
  }
}

// ---------------------------------------------------------------------------
// combine + final 64x64 projection
// ---------------------------------------------------------------------------
__global__ __launch_bounds__(256) void combine_proj(
    const float* __restrict__ eo, const int* __restrict__ tok_slot,
    const float* __restrict__ pw, const float* __restrict__ pb,
    float* __restrict__ outp) {
  __shared__ float cs[64][68];
  __shared__ float pws[64][68];
  const int t0 = blockIdx.x * 64;
  const int tq = threadIdx.x & 3;
  const int tt = threadIdx.x >> 2;
#pragma unroll
  for (int j = 0; j < 4; ++j) {
    float4 v = *(const float4*)(pw + tt * 64 + tq * 16 + j * 4);
    *(float4*)&pws[tt][tq * 16 + j * 4] = v;
  }
  {
    int t = t0 + tt;
    int s1 = tok_slot[t * 2], s2 = tok_slot[t * 2 + 1];
#pragma unroll
    for (int j = 0; j < 4; ++j) {
      float4 a = *(const float4*)(eo + (size_t)s1 * 64 + tq * 16 + j * 4);
      float4 b = *(const float4*)(eo + (size_t)s2 * 64 + tq * 16 + j * 4);
      float4 c = {a.x + b.x, a.y + b.y, a.z + b.z, a.w + b.w};
      *(float4*)&cs[tt][tq * 16 + j * 4] = c;
    }
  }
  __syncthreads();
  float o[16];
#pragma unroll
  for (int i = 0; i < 16; ++i) o[i] = 0.f;
  for (int j = 0; j < 64; ++j) {
    float c = cs[tt][j];
#pragma unroll
    for (int q4 = 0; q4 < 4; ++q4) {
      float4 p = *(const float4*)&pws[j][tq * 16 + q4 * 4];
      o[q4 * 4 + 0] += c * p.x;
      o[q4 * 4 + 1] += c * p.y;
      o[q4 * 4 + 2] += c * p.z;
      o[q4 * 4 + 3] += c * p.w;
    }
  }
#pragma unroll
  for (int i = 0; i < 16; ++i)
    outp[(size_t)(t0 + tt) * 64 + tq * 16 + i] = o[i] + pb[tq * 16 + i];
}

// ---------------------------------------------------------------------------
extern "C" void kernel_launch(void* const* d_in, const int* in_sizes, int n_in,
                              void* d_out, int out_size, void* d_ws, size_t ws_size,
                              hipStream_t stream) {
  const float* x      = (const float*)d_in[0];
  const float* g_w1   = (const float*)d_in[1];
  const float* g_b1   = (const float*)d_in[2];
  const float* g_lng  = (const float*)d_in[3];
  const float* g_lnb  = (const float*)d_in[4];
  const float* g_w2   = (const float*)d_in[5];
  const float* g_b2   = (const float*)d_in[6];
  const float* e_w1   = (const float*)d_in[7];
  const float* e_b1   = (const float*)d_in[8];
  const float* e_ln1g = (const float*)d_in[9];
  const float* e_ln1b = (const float*)d_in[10];
  const float* e_w2   = (const float*)d_in[11];
  const float* e_b2   = (const float*)d_in[12];
  const float* e_ln2g = (const float*)d_in[13];
  const float* e_ln2b = (const float*)d_in[14];
  const float* e_w3   = (const float*)d_in[15];
  const float* e_b3   = (const float*)d_in[16];
  const float* p_w    = (const float*)d_in[17];
  const float* p_b    = (const float*)d_in[18];

  char* ws = (char*)d_ws;
  u16*   x_bf  = (u16*)(ws);                      // 16 MB
  u16*   x_lo  = (u16*)(ws + (16ull << 20));      // 16 MB
  u16*   e_w1t = (u16*)(ws + (32ull << 20));      // 4 MB
  u16*   e_w2t = (u16*)(ws + (36ull << 20));      // 4 MB
  u16*   e_w3t = (u16*)(ws + (40ull << 20));      // 0.5 MB
  u16*   wcat  = (u16*)(ws + (41ull << 20));      // 1.5 MB
  float* w2t   = (float*)(ws + (43ull << 20));    // 16 KB
  // gate partials: gh0 = ws+44MB (32MB), gh1 = gh0 + N_TOK*512 = ws+76MB
  // (CONTIGUOUS: gate split-K half y writes outf + y*osplit). h overlays
  // gh0/gh1 after gate2_topk has consumed them.
  float* gh0   = (float*)(ws + (44ull << 20));    // 44..76
  float* gh1   = (float*)(ws + (76ull << 20));    // 76..108
  u16*   h     = (u16*)(ws + (44ull << 20));      // 44..76.5 (after gate)
  float* eo    = (float*)(ws + (112ull << 20));   // 112..120.5
  int*   slot_token = (int*)(ws + (121ull << 20));
  float* slot_w     = (float*)(ws + (121ull << 20) + (1ull << 18));
  int*   tok_slot   = (int*)(ws + (121ull << 20) + (2ull << 18));
  int*   blk_cnt    = (int*)(ws + (122ull << 20));   // 512
  int*   sbase      = blk_cnt + 512;                 // 512
  int*   blk_e      = blk_cnt + 1024;                // 520
  int*   blk_tok0   = blk_cnt + 2048;                // 520
  if (ws_size < (123ull << 20)) return;

  float* fout = (float*)d_out;
  float* o_output = fout;                 // 16384*64
  float* o_gatew  = fout + 1048576;       // 16384*8
  float* o_idx    = fout + 1179648;       // 16384*2
  float* o_topw   = fout + 1212416;       // 16384*2
  float* o_usage  = fout + 1245184;       // 8

  (void)hipFuncSetAttribute((const void*)gemm_core<0, 0, 0, 0>,
                            hipFuncAttributeMaxDynamicSharedMemorySize, 73728);
  (void)hipFuncSetAttribute((const void*)gemm_core<1, 1, 1, 1>,
                            hipFuncAttributeMaxDynamicSharedMemorySize, 73728);
  (void)hipFuncSetAttribute((const void*)gemm_core<1, 0, 1, 1>,
                            hipFuncAttributeMaxDynamicSharedMemorySize, 73728);

  // ---- prep ----
  prep_x<<<8192, 256, 0, stream>>>(x, x_bf, x_lo);
  transpose_bf_tiled<<<dim3(8, 8, 8), 256, 0, stream>>>(e_w1, e_w1t, 512, 512);
  transpose_bf_tiled<<<dim3(8, 8, 8), 256, 0, stream>>>(e_w2, e_w2t, 512, 512);
  transpose_bf_tiled<<<dim3(8, 1, 8), 256, 0, stream>>>(e_w3, e_w3t, 512, 64);
  prep_wcat<<<3072, 256, 0, stream>>>(g_w1, wcat);
  prep_w2t<<<16, 256, 0, stream>>>(g_w2, w2t);

  // ---- gate: split-K (2 halves of 768), raw fp32 partials, 512 blocks ----
  gemm_core<0, 0, 0, 0><<<dim3(256, 2), 512, 73728, stream>>>(
      x_bf, x_lo, wcat, 0, 1536, 768, (long)N_TOK * 512, nullptr, 0,
      nullptr, nullptr, nullptr, gh0, nullptr, nullptr, nullptr);
  gate2_topk<<<N_TOK / 4, 256, 0, stream>>>(gh0, gh1, g_b1, g_lng, g_lnb,
                                            w2t, g_b2, o_gatew, o_idx, o_topw);
  usage_k<<<8, 256, 0, stream>>>(o_gatew, o_usage);

  // ---- routing ----
  count_hist<<<64, 256, 0, stream>>>(o_idx, blk_cnt);
  k_offsets2<<<1, 512, 0, stream>>>(blk_cnt, sbase, blk_e, blk_tok0);
  k_padinit<<<(MAX_SLOTS + 255) / 256, 256, 0, stream>>>(slot_token, slot_w);
  k_scatter2<<<64, 256, 0, stream>>>(o_idx, o_topw, sbase, slot_token, slot_w,
                                     tok_slot);

  // ---- experts (520 blocks = 2.03/CU) ----
  gemm_core<1, 1, 1, 1><<<MAX_BLOCKS, 512, 73728, stream>>>(
      x_bf, nullptr, e_w1t, 512 * 512, 512, 512, 0, e_b1, 512,
      e_ln1g, e_ln1b, h, nullptr, slot_token, blk_e, blk_tok0);
  gemm_core<1, 0, 1, 1><<<MAX_BLOCKS, 512, 73728, stream>>>(
      h, nullptr, e_w2t, 512 * 512, 512, 512, 0, e_b2, 512,
      e_ln2g, e_ln2b, h, nullptr, slot_token, blk_e, blk_tok0);
  gemm3_eo<<<MAX_BLOCKS, 256, 0, stream>>>(h, e_w3t, e_b3, slot_w, blk_e,
                                           blk_tok0, eo);
  combine_proj<<<N_TOK / 64, 256, 0, stream>>>(eo, tok_slot, p_w, p_b, o_output);
}

// Round 8
// 235.298 us; speedup vs baseline: 3.4229x; 1.0612x over previous
//
#include <hip/hip_runtime.h>
#include <hip/hip_bf16.h>

// Round 8: tile-major packed weights (contiguous 32KB B-tile streaming per
// k-step, swizzle baked in at pack time). GEMM structure = round 7.
#define N_TOK 16384
#define MAX_SLOTS 33280   // 32768 + 8*64 worst-case padding
#define MAX_BLOCKS 520    // sum ceil(cnt_e/64) <= 32768/64 + 8

typedef __attribute__((ext_vector_type(8))) short bf16x8;
typedef __attribute__((ext_vector_type(4))) float f32x4;
typedef unsigned short u16;

__device__ __forceinline__ u16 f2bf(float f) {
  __hip_bfloat16 h = __float2bfloat16(f);
  union { __hip_bfloat16 b; u16 u; } c; c.b = h; return c.u;
}
__device__ __forceinline__ float bfbits2f(u16 u) {
  return __uint_as_float(((unsigned)u) << 16);
}
__device__ __forceinline__ float gelu_erf(float x) {
  return 0.5f * x * (1.0f + erff(x * 0.70710678118654752f));
}
// tanh-approx GELU; max |err| ~3e-4 (experts only; gate keeps erf)
__device__ __forceinline__ float gelu_fast(float x) {
  float u = x * (0.79788456f + 0.035677408f * x * x);
  float ex;
  asm("v_exp_f32 %0, %1" : "=v"(ex) : "v"(-2.8853901f * u));
  float den = 1.0f + ex;
  float r;
  asm("v_rcp_f32 %0, %1" : "=v"(r) : "v"(den));
  return x * r;
}
__device__ __forceinline__ void gload16(const u16* g, char* lds) {
  __builtin_amdgcn_global_load_lds(
      (const __attribute__((address_space(1))) void*)g,
      (__attribute__((address_space(3))) void*)lds, 16, 0, 0);
}

// ---------------------------------------------------------------------------
// prep kernels
// ---------------------------------------------------------------------------
__global__ __launch_bounds__(256) void prep_x(const float* __restrict__ x,
                                              u16* __restrict__ xbf,
                                              u16* __restrict__ xlo) {
  size_t i = (size_t)blockIdx.x * 256 + threadIdx.x;
  float4 v = ((const float4*)x)[i];
  float a[4] = {v.x, v.y, v.z, v.w};
  union { u16 us[4]; unsigned long long ll; } hb, lb;
#pragma unroll
  for (int j = 0; j < 4; ++j) {
    u16 hu = f2bf(a[j]);
    hb.us[j] = hu;
    lb.us[j] = f2bf(a[j] - bfbits2f(hu));
  }
  *(unsigned long long*)(xbf + i * 4) = hb.ll;
  *(unsigned long long*)(xlo + i * 4) = lb.ll;
}

// pack W [e][R k][C n] f32 -> wp tiles: u16 offset ((e*(R/32)+t)*C + n)*32 + p*8
// slot p of (tile t, col n) holds source chunk q = p ^ ((n>>1)&3), i.e.
// source k = t*32 + q*8 + j  -> linear LDS staging yields the chunk-XOR
// swizzled layout the MFMA ds_reads expect, with CONTIGUOUS global tiles.
template <int C>
__global__ __launch_bounds__(256) void pack_w(const float* __restrict__ src,
                                              u16* __restrict__ dst, int R) {
  __shared__ float tl[64][65];
  const int e = blockIdx.z;
  const int k0 = blockIdx.x * 64, n0 = blockIdx.y * 64;
  const float* s = src + (size_t)e * R * C;
  const int tr = threadIdx.x >> 2;
  const int tc4 = (threadIdx.x & 3) * 16;
#pragma unroll
  for (int j = 0; j < 4; ++j) {
    float4 v = *(const float4*)(s + (size_t)(k0 + tr) * C + n0 + tc4 + j * 4);
    tl[tr][tc4 + j * 4 + 0] = v.x;
    tl[tr][tc4 + j * 4 + 1] = v.y;
    tl[tr][tc4 + j * 4 + 2] = v.z;
    tl[tr][tc4 + j * 4 + 3] = v.w;
  }
  __syncthreads();
  const int nl = threadIdx.x >> 2;          // n within tile
  const int kl = (threadIdx.x & 3) * 16;    // k base within tile (2 chunks)
  const int n = n0 + nl;
  const int sx = (n >> 1) & 3;
  const int t = (k0 + kl) >> 5;
  const int q0 = ((k0 + kl) & 31) >> 3;     // 0 or 2
#pragma unroll
  for (int c = 0; c < 2; ++c) {
    int q = q0 + c;
    int p = q ^ sx;
    union { u16 us[8]; unsigned long long ll[2]; } o;
#pragma unroll
    for (int j = 0; j < 8; ++j) o.us[j] = f2bf(tl[kl + c * 8 + j][nl]);
    u16* d = dst + (((size_t)e * (R / 32) + t) * C + n) * 32 + p * 8;
    ((unsigned long long*)d)[0] = o.ll[0];
    ((unsigned long long*)d)[1] = o.ll[1];
  }
}

// gate wcat packed directly: one thread per (t,n,p) chunk; dst = wp + idx*8.
// composite K=1536: k<512 hi(W[k][n]); k<1024 lo(W[k-512][n]); else hi(W[k-1024][n])
__global__ __launch_bounds__(256) void prep_wcat(const float* __restrict__ gw1,
                                                 u16* __restrict__ wp) {
  int idx = blockIdx.x * 256 + threadIdx.x;   // < 48*512*4
  int p = idx & 3;
  int n = (idx >> 2) & 511;
  int t = idx >> 11;
  int q = p ^ ((n >> 1) & 3);
  int k0 = t * 32 + q * 8;
  union { u16 us[8]; unsigned long long ll[2]; } o;
#pragma unroll
  for (int j = 0; j < 8; ++j) {
    int k = k0 + j;
    u16 v;
    if (k < 512) {
      v = f2bf(gw1[k * 512 + n]);
    } else if (k < 1024) {
      float w = gw1[(k - 512) * 512 + n];
      v = f2bf(w - bfbits2f(f2bf(w)));
    } else {
      v = f2bf(gw1[(k - 1024) * 512 + n]);
    }
    o.us[j] = v;
  }
  unsigned long long* d = (unsigned long long*)(wp + (size_t)idx * 8);
  d[0] = o.ll[0];
  d[1] = o.ll[1];
}

__global__ __launch_bounds__(256) void prep_w2t(const float* __restrict__ gw2,
                                                float* __restrict__ w2t) {
  int i = blockIdx.x * 256 + threadIdx.x;
  int e = i >> 9, k = i & 511;
  w2t[i] = gw2[k * 8 + e];
}

// ---------------------------------------------------------------------------
// core GEMM.  BM=64, BN=512, BK=32, 512 threads (8 waves, 64x64 wave tile).
// B comes from tile-major packed weights: each k-step stages one CONTIGUOUS
// 32KB tile (32 x 1KB gload16). A is gathered rows (pre-swizzled source).
// LDS dbuf 72KB -> 2 blocks/CU. LNOUT=1: +bias,LN,GELU -> bf16.
// LNOUT=0: raw fp32 partial to outf + blockIdx.y*osplit (gate K-split).
// ---------------------------------------------------------------------------
template <int ROUTED, int GATHER, int LNOUT, int FAST>
__global__ __launch_bounds__(512, 4) void gemm_core(
    const u16* __restrict__ A, const u16* __restrict__ A2,
    const u16* __restrict__ Wp, long w_estride, int klen, long osplit,
    const float* __restrict__ bias, int b_estride,
    const float* __restrict__ lng, const float* __restrict__ lnb,
    u16* __restrict__ outb, float* __restrict__ outf,
    const int* __restrict__ slot_token, const int* __restrict__ blk_e,
    const int* __restrict__ blk_tok0) {
  constexpr int ABYTES = 4096;          // 64 rows x 64B
  constexpr int BUF = ABYTES + 32768;   // + B tile 32KB
  constexpr int TSU = 16384;            // B tile size in u16 (512n x 32k)
  extern __shared__ char smem[];

  const int tid = threadIdx.x;
  const int lane = tid & 63;
  const int wv = tid >> 6;          // 0..7
  const int wn = wv * 64;
  const int l15 = lane & 15;
  const int lk = lane >> 4;
  const int swzk16 = (lk ^ ((l15 >> 1) & 3)) << 4;

  int e, row0, kt0, kbase;
  if (ROUTED) {
    e = blk_e[blockIdx.x];
    if (e < 0) return;
    row0 = blk_tok0[blockIdx.x];
    kt0 = 0; kbase = 0;
  } else {
    e = 0;
    row0 = blockIdx.x * 64;
    kbase = blockIdx.y * klen;
    kt0 = kbase >> 5;
  }
  const u16* We = Wp + (size_t)e * w_estride;

  // staging: 36 wave-loads (A:4, B:32); wave wv takes ids {wv+8i | i<5, id<36}
  const int lrq = lane >> 2;                               // row in 16-group
  const int cse = (((lane & 3) ^ ((lane >> 3) & 3)) << 3); // pre-swz elem off
  size_t off[5];
  int ldsoff[5], typ[5];  // 0=A 1=B 2=none
#pragma unroll
  for (int i = 0; i < 5; ++i) {
    int id = wv + 8 * i;
    if (id >= 36) { typ[i] = 2; off[i] = 0; ldsoff[i] = 0; continue; }
    if (id < 4) {
      int lr = id * 16 + lrq;
      long grow = GATHER ? (long)slot_token[row0 + lr] : (long)(row0 + lr);
      off[i] = (size_t)grow * 512 + cse;
      ldsoff[i] = id * 1024 + lane * 16;
      typ[i] = 0;
    } else {
      int bg = id - 4;
      off[i] = (size_t)bg * 512 + lane * 8;   // u16 offset within packed tile
      ldsoff[i] = ABYTES + bg * 1024 + lane * 16;
      typ[i] = 1;
    }
  }

  auto STAGE = [&](int t, char* b) {
    const int kg = kbase + t * 32;
    const u16* Aseg = A;
    int kc = kg;
    if (A2) {
      if (kg >= 1024) { Aseg = A2; kc = kg - 1024; }
      else if (kg >= 512) kc = kg - 512;
    }
    const u16* Bt = We + (size_t)(kt0 + t) * TSU;
#pragma unroll
    for (int i = 0; i < 5; ++i) {
      if (typ[i] == 0)      gload16(Aseg + off[i] + kc, b + ldsoff[i]);
      else if (typ[i] == 1) gload16(Bt + off[i], b + ldsoff[i]);
    }
  };

  f32x4 acc[4][4];
#pragma unroll
  for (int i = 0; i < 4; ++i)
#pragma unroll
    for (int j = 0; j < 4; ++j) acc[i][j] = (f32x4){0.f, 0.f, 0.f, 0.f};

  const int nt = klen / 32;
  char* buf0 = smem;
  char* buf1 = smem + BUF;

  STAGE(0, buf0);
  __syncthreads();
  for (int t = 0; t < nt; ++t) {
    char* cur = (t & 1) ? buf1 : buf0;
    char* nxt = (t & 1) ? buf0 : buf1;
    if (t + 1 < nt) STAGE(t + 1, nxt);
    char* cB = cur + ABYTES;
    bf16x8 af[4];
#pragma unroll
    for (int fm = 0; fm < 4; ++fm)
      af[fm] = *(const bf16x8*)(cur + (fm * 16 + l15) * 64 + swzk16);
#pragma unroll
    for (int fn = 0; fn < 4; ++fn) {
      bf16x8 bv = *(const bf16x8*)(cB + (wn + fn * 16 + l15) * 64 + swzk16);
#pragma unroll
      for (int fm = 0; fm < 4; ++fm)
        acc[fm][fn] = __builtin_amdgcn_mfma_f32_16x16x32_bf16(
            af[fm], bv, acc[fm][fn], 0, 0, 0);
    }
    __syncthreads();
  }

  if constexpr (LNOUT) {
    const float* be = bias + (size_t)e * b_estride;
    const float* ge = lng + (size_t)e * b_estride;
    const float* bbe = lnb + (size_t)e * b_estride;
    float bias_v[4], g_v[4], b_v[4];
#pragma unroll
    for (int fn = 0; fn < 4; ++fn) {
      int col = wn + fn * 16 + l15;
      bias_v[fn] = be[col]; g_v[fn] = ge[col]; b_v[fn] = bbe[col];
    }
#pragma unroll
    for (int fm = 0; fm < 4; ++fm)
#pragma unroll
      for (int fn = 0; fn < 4; ++fn)
#pragma unroll
        for (int r = 0; r < 4; ++r) acc[fm][fn][r] += bias_v[fn];

    // cross-wave LN reduction: redS1[wv*64+row] (8 partials per row)
    float* redS1 = (float*)smem;
    float* redS2 = redS1 + 8 * 64;
#pragma unroll
    for (int fm = 0; fm < 4; ++fm)
#pragma unroll
      for (int r = 0; r < 4; ++r) {
        float a1 = 0.f, a2 = 0.f;
#pragma unroll
        for (int fn = 0; fn < 4; ++fn) {
          float v = acc[fm][fn][r];
          a1 += v; a2 += v * v;
        }
#pragma unroll
        for (int m = 1; m < 16; m <<= 1) {
          a1 += __shfl_xor(a1, m, 64);
          a2 += __shfl_xor(a2, m, 64);
        }
        if (l15 == 0) {
          int row = fm * 16 + lk * 4 + r;
          redS1[wv * 64 + row] = a1;
          redS2[wv * 64 + row] = a2;
        }
      }
    __syncthreads();
#pragma unroll
    for (int fm = 0; fm < 4; ++fm)
#pragma unroll
      for (int r = 0; r < 4; ++r) {
        int row = fm * 16 + lk * 4 + r;
        float S1 = 0.f, S2 = 0.f;
#pragma unroll
        for (int q = 0; q < 8; ++q) {
          S1 += redS1[q * 64 + row];
          S2 += redS2[q * 64 + row];
        }
        float mu = S1 * (1.0f / 512.0f);
        float var = S2 * (1.0f / 512.0f) - mu * mu;
        float rs = rsqrtf(var + 1e-5f);
        size_t rowg = (size_t)(row0 + row);
#pragma unroll
        for (int fn = 0; fn < 4; ++fn) {
          int col = wn + fn * 16 + l15;
          float v = (acc[fm][fn][r] - mu) * rs * g_v[fn] + b_v[fn];
          v = FAST ? gelu_fast(v) : gelu_erf(v);
          outb[rowg * 512 + col] = f2bf(v);
        }
      }
  } else {
    float* dst = outf + (size_t)blockIdx.y * osplit;
#pragma unroll
    for (int fm = 0; fm < 4; ++fm)
#pragma unroll
      for (int r = 0; r < 4; ++r) {
        size_t rowg = (size_t)(row0 + fm * 16 + lk * 4 + r);
#pragma unroll
        for (int fn = 0; fn < 4; ++fn)
          dst[rowg * 512 + wn + fn * 16 + l15] = acc[fm][fn][r];
      }
  }
}

// ---------------------------------------------------------------------------
// gate tail: sum K-halves + bias + LN + GELU(erf) + logits + softmax + top-2
// ---------------------------------------------------------------------------
__global__ __launch_bounds__(256) void gate2_topk(
    const float* __restrict__ gh0, const float* __restrict__ gh1,
    const float* __restrict__ b1, const float* __restrict__ lng,
    const float* __restrict__ lnb, const float* __restrict__ w2t,
    const float* __restrict__ b2, float* __restrict__ gwout,
    float* __restrict__ idxout, float* __restrict__ tkwout) {
  const int lane = threadIdx.x & 63;
  const int wv = threadIdx.x >> 6;
  const int t = blockIdx.x * 4 + wv;
  const int c0 = lane * 8;
  float v[8];
  {
    float4 a0 = *(const float4*)(gh0 + (size_t)t * 512 + c0);
    float4 a1 = *(const float4*)(gh0 + (size_t)t * 512 + c0 + 4);
    float4 h0 = *(const float4*)(gh1 + (size_t)t * 512 + c0);
    float4 h1 = *(const float4*)(gh1 + (size_t)t * 512 + c0 + 4);
    float4 bb0 = *(const float4*)(b1 + c0);
    float4 bb1 = *(const float4*)(b1 + c0 + 4);
    v[0] = a0.x + h0.x + bb0.x; v[1] = a0.y + h0.y + bb0.y;
    v[2] = a0.z + h0.z + bb0.z; v[3] = a0.w + h0.w + bb0.w;
    v[4] = a1.x + h1.x + bb1.x; v[5] = a1.y + h1.y + bb1.y;
    v[6] = a1.z + h1.z + bb1.z; v[7] = a1.w + h1.w + bb1.w;
  }
  float s1 = 0.f, s2 = 0.f;
#pragma unroll
  for (int j = 0; j < 8; ++j) { s1 += v[j]; s2 += v[j] * v[j]; }
#pragma unroll
  for (int m = 1; m < 64; m <<= 1) {
    s1 += __shfl_xor(s1, m, 64);
    s2 += __shfl_xor(s2, m, 64);
  }
  float mu = s1 * (1.0f / 512.0f);
  float var = s2 * (1.0f / 512.0f) - mu * mu;
  float rs = rsqrtf(var + 1e-5f);
  float y[8];
  {
    float4 g0 = *(const float4*)(lng + c0);
    float4 g1 = *(const float4*)(lng + c0 + 4);
    float4 q0 = *(const float4*)(lnb + c0);
    float4 q1 = *(const float4*)(lnb + c0 + 4);
    float gg[8] = {g0.x, g0.y, g0.z, g0.w, g1.x, g1.y, g1.z, g1.w};
    float qq[8] = {q0.x, q0.y, q0.z, q0.w, q1.x, q1.y, q1.z, q1.w};
#pragma unroll
    for (int j = 0; j < 8; ++j)
      y[j] = gelu_erf((v[j] - mu) * rs * gg[j] + qq[j]);
  }
  float logit[8];
#pragma unroll
  for (int e = 0; e < 8; ++e) {
    const float4* wr = (const float4*)(w2t + e * 512 + c0);
    float4 w0 = wr[0], w1 = wr[1];
    float p = y[0] * w0.x + y[1] * w0.y + y[2] * w0.z + y[3] * w0.w +
              y[4] * w1.x + y[5] * w1.y + y[6] * w1.z + y[7] * w1.w;
#pragma unroll
    for (int m = 1; m < 64; m <<= 1) p += __shfl_xor(p, m, 64);
    logit[e] = p + b2[e];
  }
  if (lane == 0) {
    float mx = logit[0];
#pragma unroll
    for (int e = 1; e < 8; ++e) mx = fmaxf(mx, logit[e]);
    float w[8], ssum = 0.f;
#pragma unroll
    for (int e = 0; e < 8; ++e) { w[e] = expf(logit[e] - mx); ssum += w[e]; }
    float inv = 1.0f / ssum;
#pragma unroll
    for (int e = 0; e < 8; ++e) w[e] *= inv;
    float w1v = -1.f, w2v = -1.f; int i1 = 0, i2 = 0;
#pragma unroll
    for (int e = 0; e < 8; ++e) {
      float vv = w[e];
      if (vv > w1v)      { w2v = w1v; i2 = i1; w1v = vv; i1 = e; }
      else if (vv > w2v) { w2v = vv; i2 = e; }
    }
    float s = w1v + w2v;
#pragma unroll
    for (int e = 0; e < 8; ++e) gwout[t * 8 + e] = w[e];
    idxout[t * 2] = (float)i1; idxout[t * 2 + 1] = (float)i2;
    tkwout[t * 2] = w1v / s;   tkwout[t * 2 + 1] = w2v / s;
  }
}

__global__ __launch_bounds__(256) void usage_k(const float* __restrict__ gw,
                                               float* __restrict__ usage) {
  __shared__ float r[256];
  int e = blockIdx.x;
  float s = 0.f;
  for (int t = threadIdx.x; t < N_TOK; t += 256) s += gw[t * 8 + e];
  r[threadIdx.x] = s;
  __syncthreads();
  for (int st = 128; st > 0; st >>= 1) {
    if (threadIdx.x < st) r[threadIdx.x] += r[threadIdx.x + st];
    __syncthreads();
  }
  if (threadIdx.x == 0) usage[e] = r[0] * (1.0f / (float)N_TOK);
}

// ---------------------------------------------------------------------------
// routing (hierarchical; 64-row block granularity)
// ---------------------------------------------------------------------------
__global__ __launch_bounds__(256) void count_hist(const float* __restrict__ idxout,
                                                  int* __restrict__ blk_cnt) {
  __shared__ int h[8];
  if (threadIdx.x < 8) h[threadIdx.x] = 0;
  __syncthreads();
  int t = blockIdx.x * 256 + threadIdx.x;
  int e0 = (int)idxout[t * 2], e1 = (int)idxout[t * 2 + 1];
  atomicAdd(&h[e0], 1);
  atomicAdd(&h[e1], 1);
  __syncthreads();
  if (threadIdx.x < 8) blk_cnt[blockIdx.x * 8 + threadIdx.x] = h[threadIdx.x];
}

__global__ __launch_bounds__(512) void k_offsets2(
    const int* __restrict__ blk_cnt, int* __restrict__ sbase,
    int* __restrict__ blk_e, int* __restrict__ blk_tok0) {
  __shared__ int cnt[64][8];
  __shared__ int ecnt[8];
  __shared__ int offs[8];
  const int tid = threadIdx.x;
  cnt[tid >> 3][tid & 7] = blk_cnt[tid];
  __syncthreads();
  if (tid < 8) {
    int s = 0;
    for (int b = 0; b < 64; ++b) s += cnt[b][tid];
    ecnt[tid] = s;
  }
  __syncthreads();
  if (tid == 0) {
    int off = 0;
    for (int e = 0; e < 8; ++e) {
      offs[e] = off;
      off += ((ecnt[e] + 63) >> 6) << 6;
    }
  }
  __syncthreads();
  {
    int b = tid >> 3, e = tid & 7;
    int s = offs[e];
    for (int bp = 0; bp < b; ++bp) s += cnt[bp][e];
    sbase[tid] = s;
  }
  for (int b = tid; b < MAX_BLOCKS; b += 512) {
    int acc = 0, be = -1, bt = 0;
#pragma unroll
    for (int e = 0; e < 8; ++e) {
      int nbe = (ecnt[e] + 63) >> 6;
      if (b >= acc && b < acc + nbe) { be = e; bt = offs[e] + (b - acc) * 64; }
      acc += nbe;
    }
    blk_e[b] = be;
    blk_tok0[b] = bt;
  }
}

__global__ __launch_bounds__(256) void k_padinit(int* __restrict__ slot_token,
                                                 float* __restrict__ slot_w) {
  int i = blockIdx.x * 256 + threadIdx.x;
  if (i < MAX_SLOTS) { slot_token[i] = 0; slot_w[i] = 0.f; }
}

__global__ __launch_bounds__(256) void k_scatter2(
    const float* __restrict__ idxout, const float* __restrict__ tkwout,
    const int* __restrict__ sbase, int* __restrict__ slot_token,
    float* __restrict__ slot_w, int* __restrict__ tok_slot) {
  __shared__ int lpos[8];
  if (threadIdx.x < 8) lpos[threadIdx.x] = 0;
  __syncthreads();
  int t = blockIdx.x * 256 + threadIdx.x;
#pragma unroll
  for (int k = 0; k < 2; ++k) {
    int e = (int)idxout[t * 2 + k];
    int lr = atomicAdd(&lpos[e], 1);
    int s = sbase[blockIdx.x * 8 + e] + lr;
    slot_token[s] = t;
    slot_w[s] = tkwout[t * 2 + k];
    tok_slot[t * 2 + k] = s;
  }
}

// ---------------------------------------------------------------------------
// GEMM3: eo[slot] = slot_w * (h2[slot] @ w3[e] + b3[e]); 64-row blocks.
// B = packed w3 tiles (4KB contiguous per k-step).
// ---------------------------------------------------------------------------
__global__ __launch_bounds__(256) void gemm3_eo(
    const u16* __restrict__ h, const u16* __restrict__ w3p,
    const float* __restrict__ b3, const float* __restrict__ slot_w,
    const int* __restrict__ blk_e, const int* __restrict__ blk_tok0,
    float* __restrict__ eo) {
  __shared__ char smem[2][8192];  // A 4KB + B 4KB per buffer
  int e = blk_e[blockIdx.x];
  if (e < 0) return;
  int row0 = blk_tok0[blockIdx.x];

  const int tid = threadIdx.x;
  const int lane = tid & 63;
  const int wv = tid >> 6;   // 0..3
  const int l15 = lane & 15, lk = lane >> 4;
  const int swzk16 = (lk ^ ((l15 >> 1) & 3)) << 4;
  const u16* we = w3p + (size_t)e * 32768;   // 16 tiles x 2048 u16

  const int lrq = lane >> 2;
  const int cse = (((lane & 3) ^ ((lane >> 3) & 3)) << 3);
  size_t aoff = (size_t)(row0 + wv * 16 + lrq) * 512 + cse;
  size_t boff = (size_t)wv * 512 + lane * 8;   // within packed tile
  const int ldsA = wv * 1024 + lane * 16;
  const int ldsB = 4096 + wv * 1024 + lane * 16;

  auto STAGE = [&](int t, char* b) {
    gload16(h + aoff + t * 32, b + ldsA);
    gload16(we + (size_t)t * 2048 + boff, b + ldsB);
  };

  f32x4 acc[4];
#pragma unroll
  for (int j = 0; j < 4; ++j) acc[j] = (f32x4){0.f, 0.f, 0.f, 0.f};

  STAGE(0, smem[0]);
  __syncthreads();
  for (int t = 0; t < 16; ++t) {
    char* cur = smem[t & 1];
    if (t + 1 < 16) STAGE(t + 1, smem[(t + 1) & 1]);
    char* cB = cur + 4096;
    bf16x8 a = *(const bf16x8*)(cur + (wv * 16 + l15) * 64 + swzk16);
#pragma unroll
    for (int fn = 0; fn < 4; ++fn) {
      bf16x8 bv = *(const bf16x8*)(cB + (fn * 16 + l15) * 64 + swzk16);
      acc[fn] = __builtin_amdgcn_mfma_f32_16x16x32_bf16(a, bv, acc[fn], 0, 0, 0);
    }
    __syncthreads();
  }

#pragma unroll
  for (int r = 0; r < 4; ++r) {
    int row = wv * 16 + lk * 4 + r;
    float w = slot_w[row0 + row];
#pragma unroll
    for (int fn = 0; fn < 4; ++fn) {
      int col = fn * 16 + l15;
      eo[(size_t)(row0 + row) * 64 + col] = w * (acc[fn][r] + b3[e * 64 + col]);
    }
  }
}

// ---------------------------------------------------------------------------
// combine + final 64x64 projection
// ---------------------------------------------------------------------------
__global__ __launch_bounds__(256) void combine_proj(
    const float* __restrict__ eo, const int* __restrict__ tok_slot,
    const float* __restrict__ pw, const float* __restrict__ pb,
    float* __restrict__ outp) {
  __shared__ float cs[64][68];
  __shared__ float pws[64][68];
  const int t0 = blockIdx.x * 64;
  const int tq = threadIdx.x & 3;
  const int tt = threadIdx.x >> 2;
#pragma unroll
  for (int j = 0; j < 4; ++j) {
    float4 v = *(const float4*)(pw + tt * 64 + tq * 16 + j * 4);
    *(float4*)&pws[tt][tq * 16 + j * 4] = v;
  }
  {
    int t = t0 + tt;
    int s1 = tok_slot[t * 2], s2 = tok_slot[t * 2 + 1];
#pragma unroll
    for (int j = 0; j < 4; ++j) {
      float4 a = *(const float4*)(eo + (size_t)s1 * 64 + tq * 16 + j * 4);
      float4 b = *(const float4*)(eo + (size_t)s2 * 64 + tq * 16 + j * 4);
      float4 c = {a.x + b.x, a.y + b.y, a.z + b.z, a.w + b.w};
      *(float4*)&cs[tt][tq * 16 + j * 4] = c;
    }
  }
  __syncthreads();
  float o[16];
#pragma unroll
  for (int i = 0; i < 16; ++i) o[i] = 0.f;
  for (int j = 0; j < 64; ++j) {
    float c = cs[tt][j];
#pragma unroll
    for (int q4 = 0; q4 < 4; ++q4) {
      float4 p = *(const float4*)&pws[j][tq * 16 + q4 * 4];
      o[q4 * 4 + 0] += c * p.x;
      o[q4 * 4 + 1] += c * p.y;
      o[q4 * 4 + 2] += c * p.z;
      o[q4 * 4 + 3] += c * p.w;
    }
  }
#pragma unroll
  for (int i = 0; i < 16; ++i)
    outp[(size_t)(t0 + tt) * 64 + tq * 16 + i] = o[i] + pb[tq * 16 + i];
}

// ---------------------------------------------------------------------------
extern "C" void kernel_launch(void* const* d_in, const int* in_sizes, int n_in,
                              void* d_out, int out_size, void* d_ws, size_t ws_size,
                              hipStream_t stream) {
  const float* x      = (const float*)d_in[0];
  const float* g_w1   = (const float*)d_in[1];
  const float* g_b1   = (const float*)d_in[2];
  const float* g_lng  = (const float*)d_in[3];
  const float* g_lnb  = (const float*)d_in[4];
  const float* g_w2   = (const float*)d_in[5];
  const float* g_b2   = (const float*)d_in[6];
  const float* e_w1   = (const float*)d_in[7];
  const float* e_b1   = (const float*)d_in[8];
  const float* e_ln1g = (const float*)d_in[9];
  const float* e_ln1b = (const float*)d_in[10];
  const float* e_w2   = (const float*)d_in[11];
  const float* e_b2   = (const float*)d_in[12];
  const float* e_ln2g = (const float*)d_in[13];
  const float* e_ln2b = (const float*)d_in[14];
  const float* e_w3   = (const float*)d_in[15];
  const float* e_b3   = (const float*)d_in[16];
  const float* p_w    = (const float*)d_in[17];
  const float* p_b    = (const float*)d_in[18];

  char* ws = (char*)d_ws;
  u16*   x_bf  = (u16*)(ws);                      // 16 MB
  u16*   x_lo  = (u16*)(ws + (16ull << 20));      // 16 MB
  u16*   e_w1p = (u16*)(ws + (32ull << 20));      // 4 MB (packed tiles)
  u16*   e_w2p = (u16*)(ws + (36ull << 20));      // 4 MB
  u16*   e_w3p = (u16*)(ws + (40ull << 20));      // 0.5 MB
  u16*   wcat  = (u16*)(ws + (41ull << 20));      // 1.5 MB (packed tiles)
  float* w2t   = (float*)(ws + (43ull << 20));    // 16 KB
  // gate partials: gh0 = ws+44MB (32MB), gh1 = gh0 + N_TOK*512 = ws+76MB
  // (contiguous: split-K half y writes outf + y*osplit). h overlays after.
  float* gh0   = (float*)(ws + (44ull << 20));    // 44..76
  float* gh1   = (float*)(ws + (76ull << 20));    // 76..108
  u16*   h     = (u16*)(ws + (44ull << 20));      // 44..76.5 (after gate)
  float* eo    = (float*)(ws + (112ull << 20));   // 112..120.5
  int*   slot_token = (int*)(ws + (121ull << 20));
  float* slot_w     = (float*)(ws + (121ull << 20) + (1ull << 18));
  int*   tok_slot   = (int*)(ws + (121ull << 20) + (2ull << 18));
  int*   blk_cnt    = (int*)(ws + (122ull << 20));   // 512
  int*   sbase      = blk_cnt + 512;                 // 512
  int*   blk_e      = blk_cnt + 1024;                // 520
  int*   blk_tok0   = blk_cnt + 2048;                // 520
  if (ws_size < (123ull << 20)) return;

  float* fout = (float*)d_out;
  float* o_output = fout;                 // 16384*64
  float* o_gatew  = fout + 1048576;       // 16384*8
  float* o_idx    = fout + 1179648;       // 16384*2
  float* o_topw   = fout + 1212416;       // 16384*2
  float* o_usage  = fout + 1245184;       // 8

  (void)hipFuncSetAttribute((const void*)gemm_core<0, 0, 0, 0>,
                            hipFuncAttributeMaxDynamicSharedMemorySize, 73728);
  (void)hipFuncSetAttribute((const void*)gemm_core<1, 1, 1, 1>,
                            hipFuncAttributeMaxDynamicSharedMemorySize, 73728);
  (void)hipFuncSetAttribute((const void*)gemm_core<1, 0, 1, 1>,
                            hipFuncAttributeMaxDynamicSharedMemorySize, 73728);

  // ---- prep ----
  prep_x<<<8192, 256, 0, stream>>>(x, x_bf, x_lo);
  pack_w<512><<<dim3(8, 8, 8), 256, 0, stream>>>(e_w1, e_w1p, 512);
  pack_w<512><<<dim3(8, 8, 8), 256, 0, stream>>>(e_w2, e_w2p, 512);
  pack_w<64><<<dim3(8, 1, 8), 256, 0, stream>>>(e_w3, e_w3p, 512);
  prep_wcat<<<384, 256, 0, stream>>>(g_w1, wcat);
  prep_w2t<<<16, 256, 0, stream>>>(g_w2, w2t);

  // ---- gate: split-K (2 halves of 768), raw fp32 partials, 512 blocks ----
  gemm_core<0, 0, 0, 0><<<dim3(256, 2), 512, 73728, stream>>>(
      x_bf, x_lo, wcat, 0, 768, (long)N_TOK * 512, nullptr, 0,
      nullptr, nullptr, nullptr, gh0, nullptr, nullptr, nullptr);
  gate2_topk<<<N_TOK / 4, 256, 0, stream>>>(gh0, gh1, g_b1, g_lng, g_lnb,
                                            w2t, g_b2, o_gatew, o_idx, o_topw);
  usage_k<<<8, 256, 0, stream>>>(o_gatew, o_usage);

  // ---- routing ----
  count_hist<<<64, 256, 0, stream>>>(o_idx, blk_cnt);
  k_offsets2<<<1, 512, 0, stream>>>(blk_cnt, sbase, blk_e, blk_tok0);
  k_padinit<<<(MAX_SLOTS + 255) / 256, 256, 0, stream>>>(slot_token, slot_w);
  k_scatter2<<<64, 256, 0, stream>>>(o_idx, o_topw, sbase, slot_token, slot_w,
                                     tok_slot);

  // ---- experts ----
  gemm_core<1, 1, 1, 1><<<MAX_BLOCKS, 512, 73728, stream>>>(
      x_bf, nullptr, e_w1p, 512 * 512, 512, 0, e_b1, 512,
      e_ln1g, e_ln1b, h, nullptr, slot_token, blk_e, blk_tok0);
  gemm_core<1, 0, 1, 1><<<MAX_BLOCKS, 512, 73728, stream>>>(
      h, nullptr, e_w2p, 512 * 512, 512, 0, e_b2, 512,
      e_ln2g, e_ln2b, h, nullptr, slot_token, blk_e, blk_tok0);
  gemm3_eo<<<MAX_BLOCKS, 256, 0, stream>>>(h, e_w3p, e_b3, slot_w, blk_e,
                                           blk_tok0, eo);
  combine_proj<<<N_TOK / 64, 256, 0, stream>>>(eo, tok_slot, p_w, p_b, o_output);
}

// Round 9
// 208.454 us; speedup vs baseline: 3.8637x; 1.1288x over previous
//
#include <hip/hip_runtime.h>
#include <hip/hip_bf16.h>

// Round 9: tail-free grids. Experts BM=160 (<=212 tiles <= 256 CUs, 1/CU,
// wave 80x128), gate BM=128 x ksplit2 (256 blocks). gemm3 on 160-row tiles.
#define N_TOK 16384
#define MAX_SLOTS 34080   // 32768 + 8*159 worst-case padding (160-aligned)
#define MAX_BLOCKS 216    // sum ceil(cnt_e/160) <= 204+8 = 212

typedef __attribute__((ext_vector_type(8))) short bf16x8;
typedef __attribute__((ext_vector_type(4))) float f32x4;
typedef unsigned short u16;

__device__ __forceinline__ u16 f2bf(float f) {
  __hip_bfloat16 h = __float2bfloat16(f);
  union { __hip_bfloat16 b; u16 u; } c; c.b = h; return c.u;
}
__device__ __forceinline__ float bfbits2f(u16 u) {
  return __uint_as_float(((unsigned)u) << 16);
}
__device__ __forceinline__ float gelu_erf(float x) {
  return 0.5f * x * (1.0f + erff(x * 0.70710678118654752f));
}
// tanh-approx GELU; max |err| ~3e-4 (experts only; gate keeps erf)
__device__ __forceinline__ float gelu_fast(float x) {
  float u = x * (0.79788456f + 0.035677408f * x * x);
  float ex;
  asm("v_exp_f32 %0, %1" : "=v"(ex) : "v"(-2.8853901f * u));
  float den = 1.0f + ex;
  float r;
  asm("v_rcp_f32 %0, %1" : "=v"(r) : "v"(den));
  return x * r;
}
__device__ __forceinline__ void gload16(const u16* g, char* lds) {
  __builtin_amdgcn_global_load_lds(
      (const __attribute__((address_space(1))) void*)g,
      (__attribute__((address_space(3))) void*)lds, 16, 0, 0);
}

// ---------------------------------------------------------------------------
// prep kernels
// ---------------------------------------------------------------------------
__global__ __launch_bounds__(256) void prep_x(const float* __restrict__ x,
                                              u16* __restrict__ xbf,
                                              u16* __restrict__ xlo) {
  size_t i = (size_t)blockIdx.x * 256 + threadIdx.x;
  float4 v = ((const float4*)x)[i];
  float a[4] = {v.x, v.y, v.z, v.w};
  union { u16 us[4]; unsigned long long ll; } hb, lb;
#pragma unroll
  for (int j = 0; j < 4; ++j) {
    u16 hu = f2bf(a[j]);
    hb.us[j] = hu;
    lb.us[j] = f2bf(a[j] - bfbits2f(hu));
  }
  *(unsigned long long*)(xbf + i * 4) = hb.ll;
  *(unsigned long long*)(xlo + i * 4) = lb.ll;
}

// pack W [e][R k][C n] f32 -> tile-major swizzled bf16 (see round 8)
template <int C>
__global__ __launch_bounds__(256) void pack_w(const float* __restrict__ src,
                                              u16* __restrict__ dst, int R) {
  __shared__ float tl[64][65];
  const int e = blockIdx.z;
  const int k0 = blockIdx.x * 64, n0 = blockIdx.y * 64;
  const float* s = src + (size_t)e * R * C;
  const int tr = threadIdx.x >> 2;
  const int tc4 = (threadIdx.x & 3) * 16;
#pragma unroll
  for (int j = 0; j < 4; ++j) {
    float4 v = *(const float4*)(s + (size_t)(k0 + tr) * C + n0 + tc4 + j * 4);
    tl[tr][tc4 + j * 4 + 0] = v.x;
    tl[tr][tc4 + j * 4 + 1] = v.y;
    tl[tr][tc4 + j * 4 + 2] = v.z;
    tl[tr][tc4 + j * 4 + 3] = v.w;
  }
  __syncthreads();
  const int nl = threadIdx.x >> 2;
  const int kl = (threadIdx.x & 3) * 16;
  const int n = n0 + nl;
  const int sx = (n >> 1) & 3;
  const int t = (k0 + kl) >> 5;
  const int q0 = ((k0 + kl) & 31) >> 3;
#pragma unroll
  for (int c = 0; c < 2; ++c) {
    int q = q0 + c;
    int p = q ^ sx;
    union { u16 us[8]; unsigned long long ll[2]; } o;
#pragma unroll
    for (int j = 0; j < 8; ++j) o.us[j] = f2bf(tl[kl + c * 8 + j][nl]);
    u16* d = dst + (((size_t)e * (R / 32) + t) * C + n) * 32 + p * 8;
    ((unsigned long long*)d)[0] = o.ll[0];
    ((unsigned long long*)d)[1] = o.ll[1];
  }
}

// gate wcat packed directly (composite K=1536 split-bf16; see round 8)
__global__ __launch_bounds__(256) void prep_wcat(const float* __restrict__ gw1,
                                                 u16* __restrict__ wp) {
  int idx = blockIdx.x * 256 + threadIdx.x;   // < 48*512*4
  int p = idx & 3;
  int n = (idx >> 2) & 511;
  int t = idx >> 11;
  int q = p ^ ((n >> 1) & 3);
  int k0 = t * 32 + q * 8;
  union { u16 us[8]; unsigned long long ll[2]; } o;
#pragma unroll
  for (int j = 0; j < 8; ++j) {
    int k = k0 + j;
    u16 v;
    if (k < 512) {
      v = f2bf(gw1[k * 512 + n]);
    } else if (k < 1024) {
      float w = gw1[(k - 512) * 512 + n];
      v = f2bf(w - bfbits2f(f2bf(w)));
    } else {
      v = f2bf(gw1[(k - 1024) * 512 + n]);
    }
    o.us[j] = v;
  }
  unsigned long long* d = (unsigned long long*)(wp + (size_t)idx * 8);
  d[0] = o.ll[0];
  d[1] = o.ll[1];
}

__global__ __launch_bounds__(256) void prep_w2t(const float* __restrict__ gw2,
                                                float* __restrict__ w2t) {
  int i = blockIdx.x * 256 + threadIdx.x;
  int e = i >> 9, k = i & 511;
  w2t[i] = gw2[k * 8 + e];
}

// ---------------------------------------------------------------------------
// core GEMM.  BM=FM*32, BN=512, BK=32, 512 threads / 8 waves (2m x 4n),
// wave tile (FM*16) x 128.  1 block/CU, tail-free grids.  Packed B tiles
// (contiguous 32KB/k-step), chunk-XOR swizzle baked in.  LNOUT=1: +bias,
// LN(512), GELU -> bf16.  LNOUT=0: raw fp32 partials (gate K-split).
// ---------------------------------------------------------------------------
template <int FM, int ROUTED, int GATHER, int LNOUT, int FAST>
__global__ __launch_bounds__(512, 2) void gemm_core(
    const u16* __restrict__ A, const u16* __restrict__ A2,
    const u16* __restrict__ Wp, long w_estride, int klen, long osplit,
    const float* __restrict__ bias, int b_estride,
    const float* __restrict__ lng, const float* __restrict__ lnb,
    u16* __restrict__ outb, float* __restrict__ outf,
    const int* __restrict__ slot_token, const int* __restrict__ blk_e,
    const int* __restrict__ blk_tok0) {
  constexpr int BM = FM * 32;
  constexpr int AG = FM * 2;            // A 16-row groups
  constexpr int ABYTES = BM * 64;
  constexpr int BUF = ABYTES + 32768;
  constexpr int NL = AG + 32;           // wave-loads per k-step
  constexpr int L = (NL + 7) / 8;
  constexpr int TSU = 16384;            // packed B tile u16 count
  extern __shared__ char smem[];

  const int tid = threadIdx.x;
  const int lane = tid & 63;
  const int wv = tid >> 6;              // 0..7
  const int wm = (wv & 1) * (FM * 16);
  const int wn = (wv >> 1) * 128;
  const int l15 = lane & 15;
  const int lk = lane >> 4;
  const int swzk16 = (lk ^ ((l15 >> 1) & 3)) << 4;

  int e, row0, kt0, kbase;
  if (ROUTED) {
    e = blk_e[blockIdx.x];
    if (e < 0) return;
    row0 = blk_tok0[blockIdx.x];
    kt0 = 0; kbase = 0;
  } else {
    e = 0;
    row0 = blockIdx.x * BM;
    kbase = blockIdx.y * klen;
    kt0 = kbase >> 5;
  }
  const u16* We = Wp + (size_t)e * w_estride;

  const int lrq = lane >> 2;
  const int cse = (((lane & 3) ^ ((lane >> 3) & 3)) << 3);
  size_t off[L];
  int ldsoff[L], typ[L];  // 0=A 1=B 2=none
#pragma unroll
  for (int i = 0; i < L; ++i) {
    int id = wv + 8 * i;
    if (id >= NL) { typ[i] = 2; off[i] = 0; ldsoff[i] = 0; continue; }
    if (id < AG) {
      int lr = id * 16 + lrq;
      long grow = GATHER ? (long)slot_token[row0 + lr] : (long)(row0 + lr);
      off[i] = (size_t)grow * 512 + cse;
      ldsoff[i] = id * 1024 + lane * 16;
      typ[i] = 0;
    } else {
      int bg = id - AG;
      off[i] = (size_t)bg * 512 + lane * 8;
      ldsoff[i] = ABYTES + bg * 1024 + lane * 16;
      typ[i] = 1;
    }
  }

  auto STAGE = [&](int t, char* b) {
    const int kg = kbase + t * 32;
    const u16* Aseg = A;
    int kc = kg;
    if (A2) {
      if (kg >= 1024) { Aseg = A2; kc = kg - 1024; }
      else if (kg >= 512) kc = kg - 512;
    }
    const u16* Bt = We + (size_t)(kt0 + t) * TSU;
#pragma unroll
    for (int i = 0; i < L; ++i) {
      if (typ[i] == 0)      gload16(Aseg + off[i] + kc, b + ldsoff[i]);
      else if (typ[i] == 1) gload16(Bt + off[i], b + ldsoff[i]);
    }
  };

  f32x4 acc[FM][8];
#pragma unroll
  for (int i = 0; i < FM; ++i)
#pragma unroll
    for (int j = 0; j < 8; ++j) acc[i][j] = (f32x4){0.f, 0.f, 0.f, 0.f};

  const int nt = klen / 32;
  char* buf0 = smem;
  char* buf1 = smem + BUF;

  STAGE(0, buf0);
  __syncthreads();
  for (int t = 0; t < nt; ++t) {
    char* cur = (t & 1) ? buf1 : buf0;
    char* nxt = (t & 1) ? buf0 : buf1;
    if (t + 1 < nt) STAGE(t + 1, nxt);
    char* cB = cur + ABYTES;
    bf16x8 af[FM];
#pragma unroll
    for (int fm = 0; fm < FM; ++fm)
      af[fm] = *(const bf16x8*)(cur + (wm + fm * 16 + l15) * 64 + swzk16);
#pragma unroll
    for (int fn = 0; fn < 8; ++fn) {
      bf16x8 bv = *(const bf16x8*)(cB + (wn + fn * 16 + l15) * 64 + swzk16);
#pragma unroll
      for (int fm = 0; fm < FM; ++fm)
        acc[fm][fn] = __builtin_amdgcn_mfma_f32_16x16x32_bf16(
            af[fm], bv, acc[fm][fn], 0, 0, 0);
    }
    __syncthreads();
  }

  if constexpr (LNOUT) {
    const float* be = bias + (size_t)e * b_estride;
    const float* ge = lng + (size_t)e * b_estride;
    const float* bbe = lnb + (size_t)e * b_estride;
    float bias_v[8], g_v[8], b_v[8];
#pragma unroll
    for (int fn = 0; fn < 8; ++fn) {
      int col = wn + fn * 16 + l15;
      bias_v[fn] = be[col]; g_v[fn] = ge[col]; b_v[fn] = bbe[col];
    }
#pragma unroll
    for (int fm = 0; fm < FM; ++fm)
#pragma unroll
      for (int fn = 0; fn < 8; ++fn)
#pragma unroll
        for (int r = 0; r < 4; ++r) acc[fm][fn][r] += bias_v[fn];

    // LN reduction: 4 n-groups (wv>>1) x BM rows, conflict-free layout
    float* redS1 = (float*)smem;
    float* redS2 = redS1 + 4 * BM;
    const int g = wv >> 1;
#pragma unroll
    for (int fm = 0; fm < FM; ++fm)
#pragma unroll
      for (int r = 0; r < 4; ++r) {
        float a1 = 0.f, a2 = 0.f;
#pragma unroll
        for (int fn = 0; fn < 8; ++fn) {
          float v = acc[fm][fn][r];
          a1 += v; a2 += v * v;
        }
#pragma unroll
        for (int m = 1; m < 16; m <<= 1) {
          a1 += __shfl_xor(a1, m, 64);
          a2 += __shfl_xor(a2, m, 64);
        }
        if (l15 == 0) {
          int row = wm + fm * 16 + lk * 4 + r;
          redS1[g * BM + row] = a1;
          redS2[g * BM + row] = a2;
        }
      }
    __syncthreads();
#pragma unroll
    for (int fm = 0; fm < FM; ++fm)
#pragma unroll
      for (int r = 0; r < 4; ++r) {
        int row = wm + fm * 16 + lk * 4 + r;
        float S1 = 0.f, S2 = 0.f;
#pragma unroll
        for (int q = 0; q < 4; ++q) {
          S1 += redS1[q * BM + row];
          S2 += redS2[q * BM + row];
        }
        float mu = S1 * (1.0f / 512.0f);
        float var = S2 * (1.0f / 512.0f) - mu * mu;
        float rs = rsqrtf(var + 1e-5f);
        size_t rowg = (size_t)(row0 + row);
#pragma unroll
        for (int fn = 0; fn < 8; ++fn) {
          int col = wn + fn * 16 + l15;
          float v = (acc[fm][fn][r] - mu) * rs * g_v[fn] + b_v[fn];
          v = FAST ? gelu_fast(v) : gelu_erf(v);
          outb[rowg * 512 + col] = f2bf(v);
        }
      }
  } else {
    float* dst = outf + (size_t)blockIdx.y * osplit;
#pragma unroll
    for (int fm = 0; fm < FM; ++fm)
#pragma unroll
      for (int r = 0; r < 4; ++r) {
        size_t rowg = (size_t)(row0 + wm + fm * 16 + lk * 4 + r);
#pragma unroll
        for (int fn = 0; fn < 8; ++fn)
          dst[rowg * 512 + wn + fn * 16 + l15] = acc[fm][fn][r];
      }
  }
}

// ---------------------------------------------------------------------------
// gate tail: sum K-halves + bias + LN + GELU(erf) + logits + softmax + top-2
// ---------------------------------------------------------------------------
__global__ __launch_bounds__(256) void gate2_topk(
    const float* __restrict__ gh0, const float* __restrict__ gh1,
    const float* __restrict__ b1, const float* __restrict__ lng,
    const float* __restrict__ lnb, const float* __restrict__ w2t,
    const float* __restrict__ b2, float* __restrict__ gwout,
    float* __restrict__ idxout, float* __restrict__ tkwout) {
  const int lane = threadIdx.x & 63;
  const int wv = threadIdx.x >> 6;
  const int t = blockIdx.x * 4 + wv;
  const int c0 = lane * 8;
  float v[8];
  {
    float4 a0 = *(const float4*)(gh0 + (size_t)t * 512 + c0);
    float4 a1 = *(const float4*)(gh0 + (size_t)t * 512 + c0 + 4);
    float4 h0 = *(const float4*)(gh1 + (size_t)t * 512 + c0);
    float4 h1 = *(const float4*)(gh1 + (size_t)t * 512 + c0 + 4);
    float4 bb0 = *(const float4*)(b1 + c0);
    float4 bb1 = *(const float4*)(b1 + c0 + 4);
    v[0] = a0.x + h0.x + bb0.x; v[1] = a0.y + h0.y + bb0.y;
    v[2] = a0.z + h0.z + bb0.z; v[3] = a0.w + h0.w + bb0.w;
    v[4] = a1.x + h1.x + bb1.x; v[5] = a1.y + h1.y + bb1.y;
    v[6] = a1.z + h1.z + bb1.z; v[7] = a1.w + h1.w + bb1.w;
  }
  float s1 = 0.f, s2 = 0.f;
#pragma unroll
  for (int j = 0; j < 8; ++j) { s1 += v[j]; s2 += v[j] * v[j]; }
#pragma unroll
  for (int m = 1; m < 64; m <<= 1) {
    s1 += __shfl_xor(s1, m, 64);
    s2 += __shfl_xor(s2, m, 64);
  }
  float mu = s1 * (1.0f / 512.0f);
  float var = s2 * (1.0f / 512.0f) - mu * mu;
  float rs = rsqrtf(var + 1e-5f);
  float y[8];
  {
    float4 g0 = *(const float4*)(lng + c0);
    float4 g1 = *(const float4*)(lng + c0 + 4);
    float4 q0 = *(const float4*)(lnb + c0);
    float4 q1 = *(const float4*)(lnb + c0 + 4);
    float gg[8] = {g0.x, g0.y, g0.z, g0.w, g1.x, g1.y, g1.z, g1.w};
    float qq[8] = {q0.x, q0.y, q0.z, q0.w, q1.x, q1.y, q1.z, q1.w};
#pragma unroll
    for (int j = 0; j < 8; ++j)
      y[j] = gelu_erf((v[j] - mu) * rs * gg[j] + qq[j]);
  }
  float logit[8];
#pragma unroll
  for (int e = 0; e < 8; ++e) {
    const float4* wr = (const float4*)(w2t + e * 512 + c0);
    float4 w0 = wr[0], w1 = wr[1];
    float p = y[0] * w0.x + y[1] * w0.y + y[2] * w0.z + y[3] * w0.w +
              y[4] * w1.x + y[5] * w1.y + y[6] * w1.z + y[7] * w1.w;
#pragma unroll
    for (int m = 1; m < 64; m <<= 1) p += __shfl_xor(p, m, 64);
    logit[e] = p + b2[e];
  }
  if (lane == 0) {
    float mx = logit[0];
#pragma unroll
    for (int e = 1; e < 8; ++e) mx = fmaxf(mx, logit[e]);
    float w[8], ssum = 0.f;
#pragma unroll
    for (int e = 0; e < 8; ++e) { w[e] = expf(logit[e] - mx); ssum += w[e]; }
    float inv = 1.0f / ssum;
#pragma unroll
    for (int e = 0; e < 8; ++e) w[e] *= inv;
    float w1v = -1.f, w2v = -1.f; int i1 = 0, i2 = 0;
#pragma unroll
    for (int e = 0; e < 8; ++e) {
      float vv = w[e];
      if (vv > w1v)      { w2v = w1v; i2 = i1; w1v = vv; i1 = e; }
      else if (vv > w2v) { w2v = vv; i2 = e; }
    }
    float s = w1v + w2v;
#pragma unroll
    for (int e = 0; e < 8; ++e) gwout[t * 8 + e] = w[e];
    idxout[t * 2] = (float)i1; idxout[t * 2 + 1] = (float)i2;
    tkwout[t * 2] = w1v / s;   tkwout[t * 2 + 1] = w2v / s;
  }
}

__global__ __launch_bounds__(256) void usage_k(const float* __restrict__ gw,
                                               float* __restrict__ usage) {
  __shared__ float r[256];
  int e = blockIdx.x;
  float s = 0.f;
  for (int t = threadIdx.x; t < N_TOK; t += 256) s += gw[t * 8 + e];
  r[threadIdx.x] = s;
  __syncthreads();
  for (int st = 128; st > 0; st >>= 1) {
    if (threadIdx.x < st) r[threadIdx.x] += r[threadIdx.x + st];
    __syncthreads();
  }
  if (threadIdx.x == 0) usage[e] = r[0] * (1.0f / (float)N_TOK);
}

// ---------------------------------------------------------------------------
// routing (hierarchical; 160-row tile granularity)
// ---------------------------------------------------------------------------
__global__ __launch_bounds__(256) void count_hist(const float* __restrict__ idxout,
                                                  int* __restrict__ blk_cnt) {
  __shared__ int h[8];
  if (threadIdx.x < 8) h[threadIdx.x] = 0;
  __syncthreads();
  int t = blockIdx.x * 256 + threadIdx.x;
  int e0 = (int)idxout[t * 2], e1 = (int)idxout[t * 2 + 1];
  atomicAdd(&h[e0], 1);
  atomicAdd(&h[e1], 1);
  __syncthreads();
  if (threadIdx.x < 8) blk_cnt[blockIdx.x * 8 + threadIdx.x] = h[threadIdx.x];
}

__global__ __launch_bounds__(512) void k_offsets2(
    const int* __restrict__ blk_cnt, int* __restrict__ sbase,
    int* __restrict__ blk_e, int* __restrict__ blk_tok0) {
  __shared__ int cnt[64][8];
  __shared__ int ecnt[8];
  __shared__ int offs[8];
  const int tid = threadIdx.x;
  cnt[tid >> 3][tid & 7] = blk_cnt[tid];
  __syncthreads();
  if (tid < 8) {
    int s = 0;
    for (int b = 0; b < 64; ++b) s += cnt[b][tid];
    ecnt[tid] = s;
  }
  __syncthreads();
  if (tid == 0) {
    int off = 0;
    for (int e = 0; e < 8; ++e) {
      offs[e] = off;
      off += ((ecnt[e] + 159) / 160) * 160;
    }
  }
  __syncthreads();
  {
    int b = tid >> 3, e = tid & 7;
    int s = offs[e];
    for (int bp = 0; bp < b; ++bp) s += cnt[bp][e];
    sbase[tid] = s;
  }
  for (int b = tid; b < MAX_BLOCKS; b += 512) {
    int acc = 0, be = -1, bt = 0;
#pragma unroll
    for (int e = 0; e < 8; ++e) {
      int nbe = (ecnt[e] + 159) / 160;
      if (b >= acc && b < acc + nbe) { be = e; bt = offs[e] + (b - acc) * 160; }
      acc += nbe;
    }
    blk_e[b] = be;
    blk_tok0[b] = bt;
  }
}

__global__ __launch_bounds__(256) void k_padinit(int* __restrict__ slot_token,
                                                 float* __restrict__ slot_w) {
  int i = blockIdx.x * 256 + threadIdx.x;
  if (i < MAX_SLOTS) { slot_token[i] = 0; slot_w[i] = 0.f; }
}

__global__ __launch_bounds__(256) void k_scatter2(
    const float* __restrict__ idxout, const float* __restrict__ tkwout,
    const int* __restrict__ sbase, int* __restrict__ slot_token,
    float* __restrict__ slot_w, int* __restrict__ tok_slot) {
  __shared__ int lpos[8];
  if (threadIdx.x < 8) lpos[threadIdx.x] = 0;
  __syncthreads();
  int t = blockIdx.x * 256 + threadIdx.x;
#pragma unroll
  for (int k = 0; k < 2; ++k) {
    int e = (int)idxout[t * 2 + k];
    int lr = atomicAdd(&lpos[e], 1);
    int s = sbase[blockIdx.x * 8 + e] + lr;
    slot_token[s] = t;
    slot_w[s] = tkwout[t * 2 + k];
    tok_slot[t * 2 + k] = s;
  }
}

// ---------------------------------------------------------------------------
// GEMM3 on 160-row tiles: eo[slot] = slot_w * (h2[slot] @ w3[e] + b3[e]).
// 512 thr / 8 waves (2m x 4n), wave 80x16. LDS 28KB dbuf -> 4 blocks/CU.
// ---------------------------------------------------------------------------
__global__ __launch_bounds__(512) void gemm3_eo(
    const u16* __restrict__ h, const u16* __restrict__ w3p,
    const float* __restrict__ b3, const float* __restrict__ slot_w,
    const int* __restrict__ blk_e, const int* __restrict__ blk_tok0,
    float* __restrict__ eo) {
  constexpr int ABYTES = 10240;          // 160 rows x 64B
  constexpr int BUF = ABYTES + 4096;     // + B tile (64 cols x 64B)
  __shared__ char smem[2][BUF];
  int e = blk_e[blockIdx.x];
  if (e < 0) return;
  int row0 = blk_tok0[blockIdx.x];

  const int tid = threadIdx.x;
  const int lane = tid & 63;
  const int wv = tid >> 6;
  const int wm = (wv & 1) * 80;
  const int wn = (wv >> 1) * 16;
  const int l15 = lane & 15, lk = lane >> 4;
  const int swzk16 = (lk ^ ((l15 >> 1) & 3)) << 4;
  const u16* we = w3p + (size_t)e * 32768;   // 16 tiles x 2048 u16

  const int lrq = lane >> 2;
  const int cse = (((lane & 3) ^ ((lane >> 3) & 3)) << 3);
  // 14 loads: A groups 0..9, B groups 10..13; ids wv + 8i, i<2, skip >=14
  size_t off[2];
  int ldsoff[2], typ[2];
#pragma unroll
  for (int i = 0; i < 2; ++i) {
    int id = wv + 8 * i;
    if (id >= 14) { typ[i] = 2; off[i] = 0; ldsoff[i] = 0; continue; }
    if (id < 10) {
      off[i] = (size_t)(row0 + id * 16 + lrq) * 512 + cse;
      ldsoff[i] = id * 1024 + lane * 16;
      typ[i] = 0;
    } else {
      int bg = id - 10;
      off[i] = (size_t)bg * 512 + lane * 8;
      ldsoff[i] = ABYTES + bg * 1024 + lane * 16;
      typ[i] = 1;
    }
  }

  auto STAGE = [&](int t, char* b) {
#pragma unroll
    for (int i = 0; i < 2; ++i) {
      if (typ[i] == 0)      gload16(h + off[i] + t * 32, b + ldsoff[i]);
      else if (typ[i] == 1) gload16(we + (size_t)t * 2048 + off[i], b + ldsoff[i]);
    }
  };

  f32x4 acc[5];
#pragma unroll
  for (int j = 0; j < 5; ++j) acc[j] = (f32x4){0.f, 0.f, 0.f, 0.f};

  STAGE(0, smem[0]);
  __syncthreads();
  for (int t = 0; t < 16; ++t) {
    char* cur = smem[t & 1];
    if (t + 1 < 16) STAGE(t + 1, smem[(t + 1) & 1]);
    char* cB = cur + ABYTES;
    bf16x8 bv = *(const bf16x8*)(cB + (wn + l15) * 64 + swzk16);
#pragma unroll
    for (int fm = 0; fm < 5; ++fm) {
      bf16x8 a = *(const bf16x8*)(cur + (wm + fm * 16 + l15) * 64 + swzk16);
      acc[fm] = __builtin_amdgcn_mfma_f32_16x16x32_bf16(a, bv, acc[fm], 0, 0, 0);
    }
    __syncthreads();
  }

#pragma unroll
  for (int fm = 0; fm < 5; ++fm)
#pragma unroll
    for (int r = 0; r < 4; ++r) {
      int row = wm + fm * 16 + lk * 4 + r;
      float w = slot_w[row0 + row];
      int col = wn + l15;
      eo[(size_t)(row0 + row) * 64 + col] = w * (acc[fm][r] + b3[e * 64 + col]);
    }
}

// ---------------------------------------------------------------------------
// combine + final 64x64 projection
// ---------------------------------------------------------------------------
__global__ __launch_bounds__(256) void combine_proj(
    const float* __restrict__ eo, const int* __restrict__ tok_slot,
    const float* __restrict__ pw, const float* __restrict__ pb,
    float* __restrict__ outp) {
  __shared__ float cs[64][68];
  __shared__ float pws[64][68];
  const int t0 = blockIdx.x * 64;
  const int tq = threadIdx.x & 3;
  const int tt = threadIdx.x >> 2;
#pragma unroll
  for (int j = 0; j < 4; ++j) {
    float4 v = *(const float4*)(pw + tt * 64 + tq * 16 + j * 4);
    *(float4*)&pws[tt][tq * 16 + j * 4] = v;
  }
  {
    int t = t0 + tt;
    int s1 = tok_slot[t * 2], s2 = tok_slot[t * 2 + 1];
#pragma unroll
    for (int j = 0; j < 4; ++j) {
      float4 a = *(const float4*)(eo + (size_t)s1 * 64 + tq * 16 + j * 4);
      float4 b = *(const float4*)(eo + (size_t)s2 * 64 + tq * 16 + j * 4);
      float4 c = {a.x + b.x, a.y + b.y, a.z + b.z, a.w + b.w};
      *(float4*)&cs[tt][tq * 16 + j * 4] = c;
    }
  }
  __syncthreads();
  float o[16];
#pragma unroll
  for (int i = 0; i < 16; ++i) o[i] = 0.f;
  for (int j = 0; j < 64; ++j) {
    float c = cs[tt][j];
#pragma unroll
    for (int q4 = 0; q4 < 4; ++q4) {
      float4 p = *(const float4*)&pws[j][tq * 16 + q4 * 4];
      o[q4 * 4 + 0] += c * p.x;
      o[q4 * 4 + 1] += c * p.y;
      o[q4 * 4 + 2] += c * p.z;
      o[q4 * 4 + 3] += c * p.w;
    }
  }
#pragma unroll
  for (int i = 0; i < 16; ++i)
    outp[(size_t)(t0 + tt) * 64 + tq * 16 + i] = o[i] + pb[tq * 16 + i];
}

// ---------------------------------------------------------------------------
extern "C" void kernel_launch(void* const* d_in, const int* in_sizes, int n_in,
                              void* d_out, int out_size, void* d_ws, size_t ws_size,
                              hipStream_t stream) {
  const float* x      = (const float*)d_in[0];
  const float* g_w1   = (const float*)d_in[1];
  const float* g_b1   = (const float*)d_in[2];
  const float* g_lng  = (const float*)d_in[3];
  const float* g_lnb  = (const float*)d_in[4];
  const float* g_w2   = (const float*)d_in[5];
  const float* g_b2   = (const float*)d_in[6];
  const float* e_w1   = (const float*)d_in[7];
  const float* e_b1   = (const float*)d_in[8];
  const float* e_ln1g = (const float*)d_in[9];
  const float* e_ln1b = (const float*)d_in[10];
  const float* e_w2   = (const float*)d_in[11];
  const float* e_b2   = (const float*)d_in[12];
  const float* e_ln2g = (const float*)d_in[13];
  const float* e_ln2b = (const float*)d_in[14];
  const float* e_w3   = (const float*)d_in[15];
  const float* e_b3   = (const float*)d_in[16];
  const float* p_w    = (const float*)d_in[17];
  const float* p_b    = (const float*)d_in[18];

  char* ws = (char*)d_ws;
  u16*   x_bf  = (u16*)(ws);                      // 16 MB
  u16*   x_lo  = (u16*)(ws + (16ull << 20));      // 16 MB
  u16*   e_w1p = (u16*)(ws + (32ull << 20));      // 4 MB (packed tiles)
  u16*   e_w2p = (u16*)(ws + (36ull << 20));      // 4 MB
  u16*   e_w3p = (u16*)(ws + (40ull << 20));      // 0.5 MB
  u16*   wcat  = (u16*)(ws + (41ull << 20));      // 1.5 MB (packed tiles)
  float* w2t   = (float*)(ws + (43ull << 20));    // 16 KB
  // gate partials: gh0 = ws+44MB, gh1 = gh0 + N_TOK*512 f32 = ws+76MB
  // (contiguous; split-K half y writes outf + y*osplit). h (up to ~35MB)
  // overlays gh0 and the head of gh1 AFTER gate2_topk has consumed them.
  float* gh0   = (float*)(ws + (44ull << 20));    // 44..76
  float* gh1   = (float*)(ws + (76ull << 20));    // 76..108
  u16*   h     = (u16*)(ws + (44ull << 20));      // 44..79 (after gate)
  float* eo    = (float*)(ws + (112ull << 20));   // 112..120.8
  int*   slot_token = (int*)(ws + (121ull << 20));
  float* slot_w     = (float*)(ws + (121ull << 20) + (1ull << 18));
  int*   tok_slot   = (int*)(ws + (121ull << 20) + (2ull << 18));
  int*   blk_cnt    = (int*)(ws + (122ull << 20));   // 512
  int*   sbase      = blk_cnt + 512;                 // 512
  int*   blk_e      = blk_cnt + 1024;                // 216
  int*   blk_tok0   = blk_cnt + 2048;                // 216
  if (ws_size < (123ull << 20)) return;

  float* fout = (float*)d_out;
  float* o_output = fout;                 // 16384*64
  float* o_gatew  = fout + 1048576;       // 16384*8
  float* o_idx    = fout + 1179648;       // 16384*2
  float* o_topw   = fout + 1212416;       // 16384*2
  float* o_usage  = fout + 1245184;       // 8

  (void)hipFuncSetAttribute((const void*)gemm_core<4, 0, 0, 0, 0>,
                            hipFuncAttributeMaxDynamicSharedMemorySize, 81920);
  (void)hipFuncSetAttribute((const void*)gemm_core<5, 1, 1, 1, 1>,
                            hipFuncAttributeMaxDynamicSharedMemorySize, 86016);
  (void)hipFuncSetAttribute((const void*)gemm_core<5, 1, 0, 1, 1>,
                            hipFuncAttributeMaxDynamicSharedMemorySize, 86016);

  // ---- prep ----
  prep_x<<<8192, 256, 0, stream>>>(x, x_bf, x_lo);
  pack_w<512><<<dim3(8, 8, 8), 256, 0, stream>>>(e_w1, e_w1p, 512);
  pack_w<512><<<dim3(8, 8, 8), 256, 0, stream>>>(e_w2, e_w2p, 512);
  pack_w<64><<<dim3(8, 1, 8), 256, 0, stream>>>(e_w3, e_w3p, 512);
  prep_wcat<<<384, 256, 0, stream>>>(g_w1, wcat);
  prep_w2t<<<16, 256, 0, stream>>>(g_w2, w2t);

  // ---- gate: BM=128, split-K (2 halves of 768) -> 256 blocks, 1/CU ----
  gemm_core<4, 0, 0, 0, 0><<<dim3(N_TOK / 128, 2), 512, 81920, stream>>>(
      x_bf, x_lo, wcat, 0, 768, (long)N_TOK * 512, nullptr, 0,
      nullptr, nullptr, nullptr, gh0, nullptr, nullptr, nullptr);
  gate2_topk<<<N_TOK / 4, 256, 0, stream>>>(gh0, gh1, g_b1, g_lng, g_lnb,
                                            w2t, g_b2, o_gatew, o_idx, o_topw);
  usage_k<<<8, 256, 0, stream>>>(o_gatew, o_usage);

  // ---- routing (160-row tiles) ----
  count_hist<<<64, 256, 0, stream>>>(o_idx, blk_cnt);
  k_offsets2<<<1, 512, 0, stream>>>(blk_cnt, sbase, blk_e, blk_tok0);
  k_padinit<<<(MAX_SLOTS + 255) / 256, 256, 0, stream>>>(slot_token, slot_w);
  k_scatter2<<<64, 256, 0, stream>>>(o_idx, o_topw, sbase, slot_token, slot_w,
                                     tok_slot);

  // ---- experts: BM=160, <=212 tiles (tail-free at 1 block/CU) ----
  gemm_core<5, 1, 1, 1, 1><<<MAX_BLOCKS, 512, 86016, stream>>>(
      x_bf, nullptr, e_w1p, 512 * 512, 512, 0, e_b1, 512,
      e_ln1g, e_ln1b, h, nullptr, slot_token, blk_e, blk_tok0);
  gemm_core<5, 1, 0, 1, 1><<<MAX_BLOCKS, 512, 86016, stream>>>(
      h, nullptr, e_w2p, 512 * 512, 512, 0, e_b2, 512,
      e_ln2g, e_ln2b, h, nullptr, slot_token, blk_e, blk_tok0);
  gemm3_eo<<<MAX_BLOCKS, 512, 0, stream>>>(h, e_w3p, e_b3, slot_w, blk_e,
                                           blk_tok0, eo);
  combine_proj<<<N_TOK / 64, 256, 0, stream>>>(eo, tok_slot, p_w, p_b, o_output);
}